// Round 8
// baseline (1197.607 us; speedup 1.0000x reference)
//
#include <hip/hip_runtime.h>
#include <hip/hip_bf16.h>

#define BB 16
#define NN 1024
#define KNN 20

// ---------------- fallback: encode ws_size into output if workspace too small ----------------
__global__ void fallback_k(float* __restrict__ out, int n, float c){
    int i = blockIdx.x*256 + threadIdx.x;
    if(i < n) out[i] = c;
}

// ---------------- transpose x [16,1024,3] -> hT [16][3][1024] ----------------
__global__ void transpose3_k(const float* __restrict__ x, float* __restrict__ hT){
    int i = blockIdx.x*256 + threadIdx.x;
    if(i < BB*NN){
        int b = i >> 10, n = i & 1023;
        #pragma unroll
        for(int d=0; d<3; d++)
            hT[((size_t)b*3 + d)*NN + n] = x[(size_t)i*3 + d];
    }
}

// ---------------- transpose hs slice [16,1024,D @stride512] -> hT [16][D][1024] ----------------
template<int D>
__global__ __launch_bounds__(256) void transpose_k(const float* __restrict__ src,  // hs + cbase
                                                   float* __restrict__ hT){
    int nt = blockIdx.x, ct = blockIdx.y, b = blockIdx.z;
    int tid = threadIdx.x;
    __shared__ float tile[64][65];
    int n0 = nt*64, c0 = ct*64;
    for(int l=tid; l<64*64; l+=256){
        int r = l>>6, c = l&63;
        tile[r][c] = src[(size_t)(b*NN + n0 + r)*512 + c0 + c];
    }
    __syncthreads();
    for(int l=tid; l<64*64; l+=256){
        int d = l>>6, n = l&63;
        hT[((size_t)b*D + c0 + d)*NN + n0 + n] = tile[n][d];
    }
}

// ---------------- squared norms from hT (coalesced; fma chain order matches knn3_k) ----------------
template<int D>
__global__ void sqnormT_k(const float* __restrict__ hT, float* __restrict__ sqn){
    int i = blockIdx.x*256 + threadIdx.x;
    if(i < BB*NN){
        int b = i >> 10, n = i & 1023;
        const float* p = hT + (size_t)b*D*NN + n;
        float s = 0.f;
        for(int d=0; d<D; d++){ float v = p[(size_t)d*NN]; s = fmaf(v, v, s); }
        sqn[i] = s;
    }
}

// ---------------- fused dist-GEMM + top-20, all-register (no LDS dist buffer) ----------------
template<int D>
__global__ __launch_bounds__(256) void knn3_k(const float* __restrict__ hT,
                                              const float* __restrict__ sqn,
                                              int* __restrict__ idx){
    const int b    = blockIdx.y;
    const int n0   = blockIdx.x * 16;
    const int tid  = threadIdx.x;
    const int lane = tid & 63;
    const int wv   = tid >> 6;

    __shared__ float rowsA[D*16];     // [d][16 rows]
    __shared__ float sqnA[16];

    const float* hTb = hT + (size_t)b*D*NN;
    for(int l=tid; l<16*D; l+=256){
        int d = l >> 4, r = l & 15;
        rowsA[d*16 + r] = hTb[(size_t)d*NN + n0 + r];
    }
    if(tid < 16) sqnA[tid] = sqn[b*NN + n0 + tid];
    __syncthreads();

    const float4* B4 = (const float4*)hTb;
    float4 acc[4][4];                  // [row r][j]
    #pragma unroll
    for(int r=0;r<4;r++)
        #pragma unroll
        for(int j=0;j<4;j++) acc[r][j] = make_float4(0.f,0.f,0.f,0.f);

    #pragma unroll 2
    for(int d=0; d<D; d++){
        float4 a4 = *(const float4*)&rowsA[d*16 + wv*4];
        float4 bv[4];
        #pragma unroll
        for(int j=0;j<4;j++) bv[j] = B4[d*256 + 64*j + lane];
        float ar[4] = {a4.x, a4.y, a4.z, a4.w};
        #pragma unroll
        for(int r=0;r<4;r++)
            #pragma unroll
            for(int j=0;j<4;j++){
                acc[r][j].x = fmaf(ar[r], bv[j].x, acc[r][j].x);
                acc[r][j].y = fmaf(ar[r], bv[j].y, acc[r][j].y);
                acc[r][j].z = fmaf(ar[r], bv[j].z, acc[r][j].z);
                acc[r][j].w = fmaf(ar[r], bv[j].w, acc[r][j].w);
            }
    }

    float4 sq[4];
    #pragma unroll
    for(int j=0;j<4;j++) sq[j] = ((const float4*)(sqn + b*NN))[64*j + lane];

    const float FMAXV = 3.402823466e38f;
    for(int r=0;r<4;r++){
        float sa = sqnA[wv*4 + r];
        float v[16];
        #pragma unroll
        for(int j=0;j<4;j++){
            v[4*j+0] = sa + sq[j].x - 2.f*acc[r][j].x;
            v[4*j+1] = sa + sq[j].y - 2.f*acc[r][j].y;
            v[4*j+2] = sa + sq[j].z - 2.f*acc[r][j].z;
            v[4*j+3] = sa + sq[j].w - 2.f*acc[r][j].w;
        }
        // top-20; ties -> lowest index (matches lax.top_k stability)
        int* out = idx + ((size_t)b*NN + n0 + wv*4 + r)*KNN;
        for(int t=0;t<KNN;t++){
            float bvv = FMAXV; int bi = 0x7fffffff;
            #pragma unroll
            for(int q=0;q<16;q++){
                if(v[q] < bvv){ bvv = v[q]; bi = 4*(lane + 64*(q>>2)) + (q&3); }
            }
            #pragma unroll
            for(int off=32; off>0; off>>=1){
                float ov = __shfl_xor(bvv, off);
                int   oi = __shfl_xor(bi, off);
                if(ov < bvv || (ov == bvv && oi < bi)){ bvv = ov; bi = oi; }
            }
            if(lane == 0) out[t] = bi;
            int ol = (bi >> 2) & 63;
            if(lane == ol){
                int q = ((bi >> 8) << 2) | (bi & 3);
                v[q] = FMAXV;
            }
        }
    }
}

// ---------------- tiled dual GEMM: T = h@theta^T ; U = h@(phi-theta)^T ----------------
template<int D, int O>
__global__ __launch_bounds__(256) void featTU_k(const float* __restrict__ h, int S,
                                                const float* __restrict__ th,
                                                const float* __restrict__ ph,
                                                float* __restrict__ T, float* __restrict__ U){
    int ot = blockIdx.x, nt = blockIdx.y;
    int tid = threadIdx.x, tx = tid & 15, ty = tid >> 4;
    __shared__ float As[64][33];
    __shared__ float Wt[64][33];
    __shared__ float Wp[64][33];
    float acct[4][4] = {};
    float accp[4][4] = {};
    for(int kk=0; kk<D; kk+=32){
        for(int l=tid; l<64*32; l+=256){
            int r = l>>5, c = l&31, d = kk + c;
            As[r][c] = (d < D) ? h[(size_t)(nt*64+r)*S + d] : 0.f;
            Wt[r][c] = (d < D) ? th[(size_t)(ot*64+r)*D + d] : 0.f;
            Wp[r][c] = (d < D) ? ph[(size_t)(ot*64+r)*D + d] : 0.f;
        }
        __syncthreads();
        #pragma unroll
        for(int k=0;k<32;k++){
            float a[4], bt[4], bp[4];
            #pragma unroll
            for(int i=0;i<4;i++) a[i]  = As[ty+16*i][k];
            #pragma unroll
            for(int j=0;j<4;j++){ bt[j] = Wt[tx+16*j][k]; bp[j] = Wp[tx+16*j][k]; }
            #pragma unroll
            for(int i=0;i<4;i++)
                #pragma unroll
                for(int j=0;j<4;j++){
                    acct[i][j] = fmaf(a[i], bt[j], acct[i][j]);
                    accp[i][j] = fmaf(a[i], bp[j], accp[i][j]);
                }
        }
        __syncthreads();
    }
    #pragma unroll
    for(int i=0;i<4;i++){
        int rw = nt*64 + ty + 16*i;
        #pragma unroll
        for(int j=0;j<4;j++){
            int o = ot*64 + tx + 16*j;
            T[(size_t)rw*O + o] = acct[i][j];
            U[(size_t)rw*O + o] = accp[i][j] - acct[i][j];
        }
    }
}

// ---------------- gather 20 neighbors of T, max, + U, leaky ----------------
template<int O>
__global__ __launch_bounds__(256) void gather2_k(const float* __restrict__ T, const float* __restrict__ U,
                                                 const int* __restrict__ idx, float* __restrict__ outp){
    constexpr int P = 256 / O;           // points per block
    int bn0 = blockIdx.x * P;
    int tid = threadIdx.x;
    int p = tid / O, o = tid % O;
    int bn = bn0 + p;
    int b  = bn >> 10;
    __shared__ int nb[P*KNN];
    if(tid < P*KNN){
        int pp = tid / KNN, k = tid % KNN;
        nb[pp*KNN + k] = idx[(size_t)(bn0+pp)*KNN + k] & (NN-1);  // mask: never faults
    }
    __syncthreads();
    const float* Tb = T + (size_t)b*NN*O;
    float m = -3.402823466e38f;
    #pragma unroll
    for(int k=0;k<KNN;k++) m = fmaxf(m, Tb[(size_t)nb[p*KNN+k]*O + o]);
    float v = m + U[(size_t)bn*O + o];
    v = (v > 0.f) ? v : 0.2f*v;
    outp[(size_t)bn*512 + o] = v;
}

// ---------------- projection GEMM: 128x128 tile, 8x8/thread, max-pool epilogue ----------------
// conflict-free fragments: cols tx*4+{0..3} and 64+tx*4+{0..3} (2-way LDS aliasing = free).
// 1D grid, ot in high bits: blocks sharing the A-tile sit 128 apart -> same XCD (L2 reuse).
__global__ __launch_bounds__(256) void proj2_k(const float* __restrict__ hs, const float* __restrict__ w,
                                               float* __restrict__ pmax){
    int bi = blockIdx.x;
    int ot = bi >> 7;             // 0..7 col tiles of 128
    int nb = bi & 127;
    int b  = nb >> 3;             // 0..15
    int nt = nb & 7;              // 0..7 row tiles of 128
    int tid = threadIdx.x;
    int tx = tid & 15, ty = tid >> 4;
    __shared__ float As[16][132];     // [k][row], padded
    __shared__ float Ws[16][132];     // [k][col]
    __shared__ float red[16][128];
    float acc[8][8] = {};
    const float* ha = hs + ((size_t)b*NN + (size_t)nt*128)*512;
    const float* wa = w + (size_t)ot*128*512;
    for(int kk=0; kk<512; kk+=16){
        __syncthreads();
        #pragma unroll
        for(int q=0; q<2; q++){
            int idx = tid + 256*q;          // 0..511: r=idx>>2 (128 rows), c0=4*(idx&3)
            int r = idx >> 2, c0 = (idx & 3)*4;
            float4 av = *(const float4*)&ha[(size_t)r*512 + kk + c0];
            float4 wv = *(const float4*)&wa[(size_t)r*512 + kk + c0];
            As[c0+0][r] = av.x; As[c0+1][r] = av.y; As[c0+2][r] = av.z; As[c0+3][r] = av.w;
            Ws[c0+0][r] = wv.x; Ws[c0+1][r] = wv.y; Ws[c0+2][r] = wv.z; Ws[c0+3][r] = wv.w;
        }
        __syncthreads();
        #pragma unroll
        for(int k=0;k<16;k++){
            float a[8], bv[8];
            *(float4*)&a[0]  = *(const float4*)&As[k][ty*8];
            *(float4*)&a[4]  = *(const float4*)&As[k][ty*8+4];
            *(float4*)&bv[0] = *(const float4*)&Ws[k][tx*4];
            *(float4*)&bv[4] = *(const float4*)&Ws[k][64 + tx*4];
            #pragma unroll
            for(int i=0;i<8;i++)
                #pragma unroll
                for(int j=0;j<8;j++) acc[i][j] = fmaf(a[i], bv[j], acc[i][j]);
        }
    }
    float cmax[8];
    #pragma unroll
    for(int j=0;j<8;j++){
        cmax[j] = acc[0][j];
        #pragma unroll
        for(int i=1;i<8;i++) cmax[j] = fmaxf(cmax[j], acc[i][j]);
    }
    __syncthreads();
    *(float4*)&red[ty][tx*4]      = make_float4(cmax[0], cmax[1], cmax[2], cmax[3]);
    *(float4*)&red[ty][64 + tx*4] = make_float4(cmax[4], cmax[5], cmax[6], cmax[7]);
    __syncthreads();
    if(tid < 128){
        float m = red[0][tid];
        #pragma unroll
        for(int r=1;r<16;r++) m = fmaxf(m, red[r][tid]);
        pmax[((size_t)b*8 + nt)*1024 + ot*128 + tid] = m;
    }
}

// ---------------- column sums of hs: colsum[16][512] (for algebraic mean-pool) ----------------
__global__ void colsum_k(const float* __restrict__ hs, float* __restrict__ colsum){
    int i = blockIdx.x*256 + threadIdx.x;   // b*512 + c
    if(i >= BB*512) return;
    int b = i >> 9, c = i & 511;
    const float* p = hs + (size_t)b*NN*512 + c;
    float s = 0.f;
    for(int n=0;n<NN;n++) s += p[(size_t)n*512];
    colsum[i] = s;
}

// ---------------- combine: max over 8 tiles; mean = colsum@w/1024; + bias ----------------
__global__ __launch_bounds__(256) void pool_final2_k(const float* __restrict__ pmax,
                                                     const float* __restrict__ colsum,
                                                     const float* __restrict__ w,
                                                     const float* __restrict__ pb,
                                                     float* __restrict__ pooled){
    int i = blockIdx.x*256 + threadIdx.x;   // b*1024 + o (block covers one b)
    int b = i >> 10, o = i & 1023;
    __shared__ float cs[512];
    for(int l=threadIdx.x; l<512; l+=256) cs[l] = colsum[b*512 + l];
    __syncthreads();
    float m = -3.402823466e38f;
    #pragma unroll
    for(int t=0;t<8;t++) m = fmaxf(m, pmax[((size_t)b*8 + t)*1024 + o]);
    float s = 0.f;
    const float4* w4 = (const float4*)(w + (size_t)o*512);
    const float4* c4 = (const float4*)cs;
    for(int d=0; d<128; d++){
        float4 wv = w4[d]; float4 cv = c4[d];
        s = fmaf(cv.x, wv.x, s); s = fmaf(cv.y, wv.y, s);
        s = fmaf(cv.z, wv.z, s); s = fmaf(cv.w, wv.w, s);
    }
    float bias = pb[o];
    pooled[b*2048 + o]        = m + bias;
    pooled[b*2048 + 1024 + o] = s * (1.f/1024.f) + bias;
}

// ---------------- head FC + BatchNorm(batch of 16) + leaky; one block per feature ----------------
template<int IN>
__global__ __launch_bounds__(256) void head_bn_k(const float* __restrict__ in, const float* __restrict__ w,
                                                 const float* __restrict__ bias, const float* __restrict__ g,
                                                 const float* __restrict__ bt, float* __restrict__ out, int OUT){
    int o = blockIdx.x;
    int tid = threadIdx.x, bb = tid >> 4, s = tid & 15;
    const float* ir = in + (size_t)bb*IN;
    const float* wr = w  + (size_t)o*IN;
    float acc = 0.f;
    for(int d=s; d<IN; d+=16) acc = fmaf(ir[d], wr[d], acc);
    #pragma unroll
    for(int off=8; off>0; off>>=1) acc += __shfl_xor(acc, off);
    __shared__ float vals[16];
    __shared__ float stats[2];
    if(s == 0) vals[bb] = acc + bias[o];
    __syncthreads();
    if(tid == 0){
        float mu = 0.f;
        for(int q=0;q<16;q++) mu += vals[q];
        mu *= (1.f/16.f);
        float var = 0.f;
        for(int q=0;q<16;q++){ float d = vals[q]-mu; var = fmaf(d,d,var); }
        var *= (1.f/16.f);
        stats[0] = mu; stats[1] = rsqrtf(var + 1e-5f);
    }
    __syncthreads();
    if(s == 0){
        float v = (vals[bb]-stats[0])*stats[1]*g[o] + bt[o];
        v = (v > 0.f) ? v : 0.2f*v;
        out[(size_t)bb*OUT + o] = v;
    }
}

// ---------------- final linear -> f32 out [16,40] ----------------
__global__ __launch_bounds__(256) void head_out_k(const float* __restrict__ in, const float* __restrict__ w,
                                                  const float* __restrict__ bias, float* __restrict__ out){
    int o = blockIdx.x;   // 40
    int tid = threadIdx.x, bb = tid >> 4, s = tid & 15;
    const float* ir = in + (size_t)bb*256;
    float acc = 0.f;
    for(int d=s; d<256; d+=16) acc = fmaf(ir[d], w[o*256+d], acc);
    #pragma unroll
    for(int off=8; off>0; off>>=1) acc += __shfl_xor(acc, off);
    if(s == 0) out[bb*40 + o] = acc + bias[o];
}

extern "C" void kernel_launch(void* const* d_in, const int* in_sizes, int n_in,
                              void* d_out, int out_size, void* d_ws, size_t ws_size,
                              hipStream_t stream) {
    const float* x       = (const float*)d_in[0];
    const float* th[4]   = {(const float*)d_in[1], (const float*)d_in[3], (const float*)d_in[5], (const float*)d_in[7]};
    const float* ph[4]   = {(const float*)d_in[2], (const float*)d_in[4], (const float*)d_in[6], (const float*)d_in[8]};
    const float* proj_w  = (const float*)d_in[9];
    const float* proj_b  = (const float*)d_in[10];
    const float* emb0_w  = (const float*)d_in[11];
    const float* emb0_b  = (const float*)d_in[12];
    const float* bn0_g   = (const float*)d_in[13];
    const float* bn0_b   = (const float*)d_in[14];
    const float* emb1_w  = (const float*)d_in[15];
    const float* emb1_b  = (const float*)d_in[16];
    const float* bn1_g   = (const float*)d_in[17];
    const float* bn1_b   = (const float*)d_in[18];
    const float* out_w   = (const float*)d_in[19];
    const float* out_b   = (const float*)d_in[20];
    float* outp = (float*)d_out;

    // workspace layout (float elements) — unchanged (guard passed at 68.5 MB)
    const size_t OFF_HS  = 0;                       // 16384 x 512 = 8,388,608
    const size_t OFF_T   = 8388608;                 // 16384 x 256 = 4,194,304
    const size_t OFF_U   = 12582912;                // 16384 x 256 = 4,194,304
    const size_t OFF_SQN = 16777216;                // 16384
    const size_t OFF_IDX = 16793600;                // 16384 x 20 ints = 327,680
    const size_t REQ_FL  = 17121280;
    const size_t REQ     = REQ_FL * 4;              // 68,485,120 bytes

    if(ws_size < REQ){
        fallback_k<<<(out_size+255)/256, 256, 0, stream>>>(outp, out_size, (float)((double)ws_size*1e-6));
        return;
    }

    float* Wf   = (float*)d_ws;
    float* hs   = Wf + OFF_HS;
    float* T    = Wf + OFF_T;
    float* U    = Wf + OFF_U;
    float* sqn  = Wf + OFF_SQN;
    int*   idxb = (int*)(Wf + OFF_IDX);
    // hT aliases T region (max 16x128x1024 = 8 MB <= 16 MB); hT dead before featTU writes T
    float* hT   = T;
    // post-layer aliases inside T region (dead after last gather)
    float* pmax   = T;                 // 16*8*1024 = 131072
    float* colsum = T + 131072;        // 16*512   = 8192
    float* pooled = T + 147456;        // 16*2048  = 32768
    float* z0     = T + 180224;        // 16*512
    float* z1     = T + 188416;        // 16*256

    // ---- layer 0: h=x (S=3,D=3) -> O=64 at hs ch 0
    transpose3_k<<<64,256,0,stream>>>(x, hT);
    sqnormT_k<3><<<64,256,0,stream>>>(hT, sqn);
    knn3_k<3><<<dim3(64,16),256,0,stream>>>(hT, sqn, idxb);
    featTU_k<3,64><<<dim3(1,256),256,0,stream>>>(x, 3, th[0], ph[0], T, U);
    gather2_k<64><<<BB*NN/4,256,0,stream>>>(T, U, idxb, hs + 0);

    // ---- layer 1: h=hs[:,0:64] (S=512,D=64) -> O=64 at ch 64
    transpose_k<64><<<dim3(16,1,16),256,0,stream>>>(hs + 0, hT);
    sqnormT_k<64><<<64,256,0,stream>>>(hT, sqn);
    knn3_k<64><<<dim3(64,16),256,0,stream>>>(hT, sqn, idxb);
    featTU_k<64,64><<<dim3(1,256),256,0,stream>>>(hs + 0, 512, th[1], ph[1], T, U);
    gather2_k<64><<<BB*NN/4,256,0,stream>>>(T, U, idxb, hs + 64);

    // ---- layer 2: h=hs[:,64:128] (D=64) -> O=128 at ch 128
    transpose_k<64><<<dim3(16,1,16),256,0,stream>>>(hs + 64, hT);
    sqnormT_k<64><<<64,256,0,stream>>>(hT, sqn);
    knn3_k<64><<<dim3(64,16),256,0,stream>>>(hT, sqn, idxb);
    featTU_k<64,128><<<dim3(2,256),256,0,stream>>>(hs + 64, 512, th[2], ph[2], T, U);
    gather2_k<128><<<BB*NN/2,256,0,stream>>>(T, U, idxb, hs + 128);

    // ---- layer 3: h=hs[:,128:256] (D=128) -> O=256 at ch 256
    transpose_k<128><<<dim3(16,2,16),256,0,stream>>>(hs + 128, hT);
    sqnormT_k<128><<<64,256,0,stream>>>(hT, sqn);
    knn3_k<128><<<dim3(64,16),256,0,stream>>>(hT, sqn, idxb);
    featTU_k<128,256><<<dim3(4,256),256,0,stream>>>(hs + 128, 512, th[3], ph[3], T, U);
    gather2_k<256><<<BB*NN,256,0,stream>>>(T, U, idxb, hs + 256);

    // ---- projection + pooling (max via tiled GEMM; mean via colsum @ w)
    proj2_k<<<1024,256,0,stream>>>(hs, proj_w, pmax);
    colsum_k<<<32,256,0,stream>>>(hs, colsum);
    pool_final2_k<<<64,256,0,stream>>>(pmax, colsum, proj_w, proj_b, pooled);

    // ---- head
    head_bn_k<2048><<<512,256,0,stream>>>(pooled, emb0_w, emb0_b, bn0_g, bn0_b, z0, 512);
    head_bn_k<512><<<256,256,0,stream>>>(z0, emb1_w, emb1_b, bn1_g, bn1_b, z1, 256);
    head_out_k<<<40,256,0,stream>>>(z1, out_w, out_b, outp);
}

// Round 9
// 1029.772 us; speedup vs baseline: 1.1630x; 1.1630x over previous
//
#include <hip/hip_runtime.h>
#include <hip/hip_bf16.h>

#define BB 16
#define NN 1024
#define KNN 20

typedef __attribute__((ext_vector_type(8))) short bf16x8;   // 8 bf16 (4 VGPRs)
typedef __attribute__((ext_vector_type(4))) float f32x4;

__device__ __forceinline__ unsigned short f2b(float f){
    __hip_bfloat16 h = __float2bfloat16(f);
    return *(unsigned short*)&h;
}

// ---------------- fallback: encode ws_size into output if workspace too small ----------------
__global__ void fallback_k(float* __restrict__ out, int n, float c){
    int i = blockIdx.x*256 + threadIdx.x;
    if(i < n) out[i] = c;
}

// ---------------- transpose x [16,1024,3] -> hT [16][3][1024] ----------------
__global__ void transpose3_k(const float* __restrict__ x, float* __restrict__ hT){
    int i = blockIdx.x*256 + threadIdx.x;
    if(i < BB*NN){
        int b = i >> 10, n = i & 1023;
        #pragma unroll
        for(int d=0; d<3; d++)
            hT[((size_t)b*3 + d)*NN + n] = x[(size_t)i*3 + d];
    }
}

// ---------------- transpose hs slice [16,1024,D @stride512] -> hT [16][D][1024] ----------------
template<int D>
__global__ __launch_bounds__(256) void transpose_k(const float* __restrict__ src,
                                                   float* __restrict__ hT){
    int nt = blockIdx.x, ct = blockIdx.y, b = blockIdx.z;
    int tid = threadIdx.x;
    __shared__ float tile[64][65];
    int n0 = nt*64, c0 = ct*64;
    for(int l=tid; l<64*64; l+=256){
        int r = l>>6, c = l&63;
        tile[r][c] = src[(size_t)(b*NN + n0 + r)*512 + c0 + c];
    }
    __syncthreads();
    for(int l=tid; l<64*64; l+=256){
        int d = l>>6, n = l&63;
        hT[((size_t)b*D + c0 + d)*NN + n0 + n] = tile[n][d];
    }
}

// ---------------- squared norms from hT (coalesced; fma chain order matches knn3_k) ----------------
template<int D>
__global__ void sqnormT_k(const float* __restrict__ hT, float* __restrict__ sqn){
    int i = blockIdx.x*256 + threadIdx.x;
    if(i < BB*NN){
        int b = i >> 10, n = i & 1023;
        const float* p = hT + (size_t)b*D*NN + n;
        float s = 0.f;
        for(int d=0; d<D; d++){ float v = p[(size_t)d*NN]; s = fmaf(v, v, s); }
        sqn[i] = s;
    }
}

// ---------------- fused dist-GEMM + top-20, all-register (no LDS dist buffer) ----------------
template<int D>
__global__ __launch_bounds__(256) void knn3_k(const float* __restrict__ hT,
                                              const float* __restrict__ sqn,
                                              int* __restrict__ idx){
    const int b    = blockIdx.y;
    const int n0   = blockIdx.x * 16;
    const int tid  = threadIdx.x;
    const int lane = tid & 63;
    const int wv   = tid >> 6;

    __shared__ float rowsA[D*16];     // [d][16 rows]
    __shared__ float sqnA[16];

    const float* hTb = hT + (size_t)b*D*NN;
    for(int l=tid; l<16*D; l+=256){
        int d = l >> 4, r = l & 15;
        rowsA[d*16 + r] = hTb[(size_t)d*NN + n0 + r];
    }
    if(tid < 16) sqnA[tid] = sqn[b*NN + n0 + tid];
    __syncthreads();

    const float4* B4 = (const float4*)hTb;
    float4 acc[4][4];                  // [row r][j]
    #pragma unroll
    for(int r=0;r<4;r++)
        #pragma unroll
        for(int j=0;j<4;j++) acc[r][j] = make_float4(0.f,0.f,0.f,0.f);

    #pragma unroll 2
    for(int d=0; d<D; d++){
        float4 a4 = *(const float4*)&rowsA[d*16 + wv*4];
        float4 bv[4];
        #pragma unroll
        for(int j=0;j<4;j++) bv[j] = B4[d*256 + 64*j + lane];
        float ar[4] = {a4.x, a4.y, a4.z, a4.w};
        #pragma unroll
        for(int r=0;r<4;r++)
            #pragma unroll
            for(int j=0;j<4;j++){
                acc[r][j].x = fmaf(ar[r], bv[j].x, acc[r][j].x);
                acc[r][j].y = fmaf(ar[r], bv[j].y, acc[r][j].y);
                acc[r][j].z = fmaf(ar[r], bv[j].z, acc[r][j].z);
                acc[r][j].w = fmaf(ar[r], bv[j].w, acc[r][j].w);
            }
    }

    float4 sq[4];
    #pragma unroll
    for(int j=0;j<4;j++) sq[j] = ((const float4*)(sqn + b*NN))[64*j + lane];

    const float FMAXV = 3.402823466e38f;
    for(int r=0;r<4;r++){
        float sa = sqnA[wv*4 + r];
        float v[16];
        #pragma unroll
        for(int j=0;j<4;j++){
            v[4*j+0] = sa + sq[j].x - 2.f*acc[r][j].x;
            v[4*j+1] = sa + sq[j].y - 2.f*acc[r][j].y;
            v[4*j+2] = sa + sq[j].z - 2.f*acc[r][j].z;
            v[4*j+3] = sa + sq[j].w - 2.f*acc[r][j].w;
        }
        // top-20; ties -> lowest index (matches lax.top_k stability)
        int* out = idx + ((size_t)b*NN + n0 + wv*4 + r)*KNN;
        for(int t=0;t<KNN;t++){
            float bvv = FMAXV; int bi = 0x7fffffff;
            #pragma unroll
            for(int q=0;q<16;q++){
                if(v[q] < bvv){ bvv = v[q]; bi = 4*(lane + 64*(q>>2)) + (q&3); }
            }
            #pragma unroll
            for(int off=32; off>0; off>>=1){
                float ov = __shfl_xor(bvv, off);
                int   oi = __shfl_xor(bi, off);
                if(ov < bvv || (ov == bvv && oi < bi)){ bvv = ov; bi = oi; }
            }
            if(lane == 0) out[t] = bi;
            int ol = (bi >> 2) & 63;
            if(lane == ol){
                int q = ((bi >> 8) << 2) | (bi & 3);
                v[q] = FMAXV;
            }
        }
    }
}

// ---------------- tiled dual GEMM: T = h@theta^T ; U = h@(phi-theta)^T ----------------
template<int D, int O>
__global__ __launch_bounds__(256) void featTU_k(const float* __restrict__ h, int S,
                                                const float* __restrict__ th,
                                                const float* __restrict__ ph,
                                                float* __restrict__ T, float* __restrict__ U){
    int ot = blockIdx.x, nt = blockIdx.y;
    int tid = threadIdx.x, tx = tid & 15, ty = tid >> 4;
    __shared__ float As[64][33];
    __shared__ float Wt[64][33];
    __shared__ float Wp[64][33];
    float acct[4][4] = {};
    float accp[4][4] = {};
    for(int kk=0; kk<D; kk+=32){
        for(int l=tid; l<64*32; l+=256){
            int r = l>>5, c = l&31, d = kk + c;
            As[r][c] = (d < D) ? h[(size_t)(nt*64+r)*S + d] : 0.f;
            Wt[r][c] = (d < D) ? th[(size_t)(ot*64+r)*D + d] : 0.f;
            Wp[r][c] = (d < D) ? ph[(size_t)(ot*64+r)*D + d] : 0.f;
        }
        __syncthreads();
        #pragma unroll
        for(int k=0;k<32;k++){
            float a[4], bt[4], bp[4];
            #pragma unroll
            for(int i=0;i<4;i++) a[i]  = As[ty+16*i][k];
            #pragma unroll
            for(int j=0;j<4;j++){ bt[j] = Wt[tx+16*j][k]; bp[j] = Wp[tx+16*j][k]; }
            #pragma unroll
            for(int i=0;i<4;i++)
                #pragma unroll
                for(int j=0;j<4;j++){
                    acct[i][j] = fmaf(a[i], bt[j], acct[i][j]);
                    accp[i][j] = fmaf(a[i], bp[j], accp[i][j]);
                }
        }
        __syncthreads();
    }
    #pragma unroll
    for(int i=0;i<4;i++){
        int rw = nt*64 + ty + 16*i;
        #pragma unroll
        for(int j=0;j<4;j++){
            int o = ot*64 + tx + 16*j;
            T[(size_t)rw*O + o] = acct[i][j];
            U[(size_t)rw*O + o] = accp[i][j] - acct[i][j];
        }
    }
}

// ---------------- gather 20 neighbors of T, max, + U, leaky ----------------
template<int O>
__global__ __launch_bounds__(256) void gather2_k(const float* __restrict__ T, const float* __restrict__ U,
                                                 const int* __restrict__ idx, float* __restrict__ outp){
    constexpr int P = 256 / O;           // points per block
    int bn0 = blockIdx.x * P;
    int tid = threadIdx.x;
    int p = tid / O, o = tid % O;
    int bn = bn0 + p;
    int b  = bn >> 10;
    __shared__ int nb[P*KNN];
    if(tid < P*KNN){
        int pp = tid / KNN, k = tid % KNN;
        nb[pp*KNN + k] = idx[(size_t)(bn0+pp)*KNN + k] & (NN-1);  // mask: never faults
    }
    __syncthreads();
    const float* Tb = T + (size_t)b*NN*O;
    float m = -3.402823466e38f;
    #pragma unroll
    for(int k=0;k<KNN;k++) m = fmaxf(m, Tb[(size_t)nb[p*KNN+k]*O + o]);
    float v = m + U[(size_t)bn*O + o];
    v = (v > 0.f) ? v : 0.2f*v;
    outp[(size_t)bn*512 + o] = v;
}

// ---------------- cast hs [16384,512] f32 -> bf16 ----------------
__global__ __launch_bounds__(256) void cast_hs_k(const float* __restrict__ hs, unsigned short* __restrict__ hb){
    int i = blockIdx.x*256 + threadIdx.x;       // i indexes groups of 8
    const float4* in4 = (const float4*)hs;
    float4 a = in4[2*i], c = in4[2*i+1];
    unsigned short t[8];
    t[0]=f2b(a.x); t[1]=f2b(a.y); t[2]=f2b(a.z); t[3]=f2b(a.w);
    t[4]=f2b(c.x); t[5]=f2b(c.y); t[6]=f2b(c.z); t[7]=f2b(c.w);
    *(ulonglong2*)&hb[8*i] = *(ulonglong2*)t;
}

// ---------------- cast proj_w [1024,512] f32 -> bf16 ----------------
__global__ __launch_bounds__(256) void cast_w_k(const float* __restrict__ w, unsigned short* __restrict__ wb){
    int i = blockIdx.x*256 + threadIdx.x;
    const float4* in4 = (const float4*)w;
    float4 a = in4[2*i], c = in4[2*i+1];
    unsigned short t[8];
    t[0]=f2b(a.x); t[1]=f2b(a.y); t[2]=f2b(a.z); t[3]=f2b(a.w);
    t[4]=f2b(c.x); t[5]=f2b(c.y); t[6]=f2b(c.z); t[7]=f2b(c.w);
    *(ulonglong2*)&wb[8*i] = *(ulonglong2*)t;
}

// ---------------- projection GEMM via bf16 MFMA: 128x128 tile, max-pool epilogue ----------------
// A[m=lane&15][k=quad*8+j] ; B[n=lane&15][k=quad*8+j] (w stored [n][k]) ;
// D: row=quad*4+reg, col=lane&15  (guide m89/m120 verified layouts).
__global__ __launch_bounds__(256) void proj3_k(const unsigned short* __restrict__ hsb,
                                               const unsigned short* __restrict__ wb,
                                               float* __restrict__ pmax){
    int bi = blockIdx.x;
    int ot = bi >> 7;             // col tile (0..7) in high bits -> A-tile sharers on same XCD
    int nb = bi & 127;
    int b  = nb >> 3, nt = nb & 7;
    int tid = threadIdx.x, lane = tid & 63, wv = tid >> 6;
    int quad = lane >> 4, m = lane & 15;

    __shared__ __align__(16) unsigned short Ab[128*40];   // row stride 40 bf16 = 80 B
    __shared__ __align__(16) unsigned short Bb[128*40];

    f32x4 acc[8][2] = {};
    const unsigned short* ha = hsb + ((size_t)(b*NN + nt*128))*512;
    const unsigned short* wa = wb + (size_t)ot*128*512;

    for(int kk=0; kk<512; kk+=32){
        __syncthreads();
        #pragma unroll
        for(int q=0; q<2; q++){
            int idx = tid + 256*q;          // 512 segs: r=idx>>2 (128 rows), sg=idx&3 (8 bf16 each)
            int r = idx >> 2, sg = idx & 3;
            ulonglong2 va = *(const ulonglong2*)&ha[(size_t)r*512 + kk + sg*8];
            ulonglong2 vw = *(const ulonglong2*)&wa[(size_t)r*512 + kk + sg*8];
            *(ulonglong2*)&Ab[r*40 + sg*8] = va;
            *(ulonglong2*)&Bb[r*40 + sg*8] = vw;
        }
        __syncthreads();
        bf16x8 bf0 = *(bf16x8*)&Bb[(wv*32 + m)*40 + quad*8];
        bf16x8 bf1 = *(bf16x8*)&Bb[(wv*32 + 16 + m)*40 + quad*8];
        #pragma unroll
        for(int rt=0; rt<8; rt++){
            bf16x8 af = *(bf16x8*)&Ab[(rt*16 + m)*40 + quad*8];
            acc[rt][0] = __builtin_amdgcn_mfma_f32_16x16x32_bf16(af, bf0, acc[rt][0], 0,0,0);
            acc[rt][1] = __builtin_amdgcn_mfma_f32_16x16x32_bf16(af, bf1, acc[rt][1], 0,0,0);
        }
    }

    // column max over the 128 rows of this tile
    #pragma unroll
    for(int ct=0; ct<2; ct++){
        float mx = acc[0][ct][0];
        #pragma unroll
        for(int rt=0; rt<8; rt++)
            #pragma unroll
            for(int r=0; r<4; r++) mx = fmaxf(mx, acc[rt][ct][r]);
        mx = fmaxf(mx, __shfl_xor(mx, 16));     // combine quads (rows quad*4+r)
        mx = fmaxf(mx, __shfl_xor(mx, 32));
        if(quad == 0)
            pmax[((size_t)b*8 + nt)*1024 + ot*128 + wv*32 + ct*16 + m] = mx;
    }
}

// ---------------- column sums of hs: colsum[16][512] (for algebraic mean-pool, fp32) ----------------
__global__ void colsum_k(const float* __restrict__ hs, float* __restrict__ colsum){
    int i = blockIdx.x*256 + threadIdx.x;   // b*512 + c
    if(i >= BB*512) return;
    int b = i >> 9, c = i & 511;
    const float* p = hs + (size_t)b*NN*512 + c;
    float s = 0.f;
    for(int n=0;n<NN;n++) s += p[(size_t)n*512];
    colsum[i] = s;
}

// ---------------- combine: max over 8 tiles; mean = colsum@w/1024 (fp32); + bias ----------------
__global__ __launch_bounds__(256) void pool_final2_k(const float* __restrict__ pmax,
                                                     const float* __restrict__ colsum,
                                                     const float* __restrict__ w,
                                                     const float* __restrict__ pb,
                                                     float* __restrict__ pooled){
    int i = blockIdx.x*256 + threadIdx.x;   // b*1024 + o (block covers one b)
    int b = i >> 10, o = i & 1023;
    __shared__ float cs[512];
    for(int l=threadIdx.x; l<512; l+=256) cs[l] = colsum[b*512 + l];
    __syncthreads();
    float m = -3.402823466e38f;
    #pragma unroll
    for(int t=0;t<8;t++) m = fmaxf(m, pmax[((size_t)b*8 + t)*1024 + o]);
    float s = 0.f;
    const float4* w4 = (const float4*)(w + (size_t)o*512);
    const float4* c4 = (const float4*)cs;
    for(int d=0; d<128; d++){
        float4 wv = w4[d]; float4 cv = c4[d];
        s = fmaf(cv.x, wv.x, s); s = fmaf(cv.y, wv.y, s);
        s = fmaf(cv.z, wv.z, s); s = fmaf(cv.w, wv.w, s);
    }
    float bias = pb[o];
    pooled[b*2048 + o]        = m + bias;
    pooled[b*2048 + 1024 + o] = s * (1.f/1024.f) + bias;
}

// ---------------- head FC + BatchNorm(batch of 16) + leaky; one block per feature ----------------
template<int IN>
__global__ __launch_bounds__(256) void head_bn_k(const float* __restrict__ in, const float* __restrict__ w,
                                                 const float* __restrict__ bias, const float* __restrict__ g,
                                                 const float* __restrict__ bt, float* __restrict__ out, int OUT){
    int o = blockIdx.x;
    int tid = threadIdx.x, bb = tid >> 4, s = tid & 15;
    const float* ir = in + (size_t)bb*IN;
    const float* wr = w  + (size_t)o*IN;
    float acc = 0.f;
    for(int d=s; d<IN; d+=16) acc = fmaf(ir[d], wr[d], acc);
    #pragma unroll
    for(int off=8; off>0; off>>=1) acc += __shfl_xor(acc, off);
    __shared__ float vals[16];
    __shared__ float stats[2];
    if(s == 0) vals[bb] = acc + bias[o];
    __syncthreads();
    if(tid == 0){
        float mu = 0.f;
        for(int q=0;q<16;q++) mu += vals[q];
        mu *= (1.f/16.f);
        float var = 0.f;
        for(int q=0;q<16;q++){ float d = vals[q]-mu; var = fmaf(d,d,var); }
        var *= (1.f/16.f);
        stats[0] = mu; stats[1] = rsqrtf(var + 1e-5f);
    }
    __syncthreads();
    if(s == 0){
        float v = (vals[bb]-stats[0])*stats[1]*g[o] + bt[o];
        v = (v > 0.f) ? v : 0.2f*v;
        out[(size_t)bb*OUT + o] = v;
    }
}

// ---------------- final linear -> f32 out [16,40] ----------------
__global__ __launch_bounds__(256) void head_out_k(const float* __restrict__ in, const float* __restrict__ w,
                                                  const float* __restrict__ bias, float* __restrict__ out){
    int o = blockIdx.x;   // 40
    int tid = threadIdx.x, bb = tid >> 4, s = tid & 15;
    const float* ir = in + (size_t)bb*256;
    float acc = 0.f;
    for(int d=s; d<256; d+=16) acc = fmaf(ir[d], w[o*256+d], acc);
    #pragma unroll
    for(int off=8; off>0; off>>=1) acc += __shfl_xor(acc, off);
    if(s == 0) out[bb*40 + o] = acc + bias[o];
}

extern "C" void kernel_launch(void* const* d_in, const int* in_sizes, int n_in,
                              void* d_out, int out_size, void* d_ws, size_t ws_size,
                              hipStream_t stream) {
    const float* x       = (const float*)d_in[0];
    const float* th[4]   = {(const float*)d_in[1], (const float*)d_in[3], (const float*)d_in[5], (const float*)d_in[7]};
    const float* ph[4]   = {(const float*)d_in[2], (const float*)d_in[4], (const float*)d_in[6], (const float*)d_in[8]};
    const float* proj_w  = (const float*)d_in[9];
    const float* proj_b  = (const float*)d_in[10];
    const float* emb0_w  = (const float*)d_in[11];
    const float* emb0_b  = (const float*)d_in[12];
    const float* bn0_g   = (const float*)d_in[13];
    const float* bn0_b   = (const float*)d_in[14];
    const float* emb1_w  = (const float*)d_in[15];
    const float* emb1_b  = (const float*)d_in[16];
    const float* bn1_g   = (const float*)d_in[17];
    const float* bn1_b   = (const float*)d_in[18];
    const float* out_w   = (const float*)d_in[19];
    const float* out_b   = (const float*)d_in[20];
    float* outp = (float*)d_out;

    // workspace layout (float elements) — unchanged (guard passed at 68.5 MB)
    const size_t OFF_HS  = 0;                       // 16384 x 512 = 8,388,608
    const size_t OFF_T   = 8388608;                 // 16384 x 256 = 4,194,304
    const size_t OFF_U   = 12582912;                // 16384 x 256 = 4,194,304
    const size_t OFF_SQN = 16777216;                // 16384
    const size_t OFF_IDX = 16793600;                // 16384 x 20 ints = 327,680
    const size_t REQ_FL  = 17121280;
    const size_t REQ     = REQ_FL * 4;              // 68,485,120 bytes

    if(ws_size < REQ){
        fallback_k<<<(out_size+255)/256, 256, 0, stream>>>(outp, out_size, (float)((double)ws_size*1e-6));
        return;
    }

    float* Wf   = (float*)d_ws;
    float* hs   = Wf + OFF_HS;
    float* T    = Wf + OFF_T;
    float* U    = Wf + OFF_U;
    float* sqn  = Wf + OFF_SQN;
    int*   idxb = (int*)(Wf + OFF_IDX);
    // hT aliases T region (max 16x128x1024 = 8 MB <= 16 MB); hT dead before featTU writes T
    float* hT   = T;
    // post-layer aliases (all dead regions by then):
    float* pmax   = T;                                  // 16*8*1024 = 131,072 fl
    float* colsum = T + 131072;                         // 8,192 fl
    float* pooled = T + 147456;                         // 32,768 fl
    float* z0     = T + 180224;
    float* z1     = T + 188416;
    unsigned short* wbf  = (unsigned short*)(T + 200704);   // 524,288 bf16 = 262,144 fl (inside T region)
    unsigned short* hsbf = (unsigned short*)U;              // 8,388,608 bf16 = U region exactly (U dead after layer 3)

    // ---- layer 0: h=x (S=3,D=3) -> O=64 at hs ch 0
    transpose3_k<<<64,256,0,stream>>>(x, hT);
    sqnormT_k<3><<<64,256,0,stream>>>(hT, sqn);
    knn3_k<3><<<dim3(64,16),256,0,stream>>>(hT, sqn, idxb);
    featTU_k<3,64><<<dim3(1,256),256,0,stream>>>(x, 3, th[0], ph[0], T, U);
    gather2_k<64><<<BB*NN/4,256,0,stream>>>(T, U, idxb, hs + 0);

    // ---- layer 1: h=hs[:,0:64] (S=512,D=64) -> O=64 at ch 64
    transpose_k<64><<<dim3(16,1,16),256,0,stream>>>(hs + 0, hT);
    sqnormT_k<64><<<64,256,0,stream>>>(hT, sqn);
    knn3_k<64><<<dim3(64,16),256,0,stream>>>(hT, sqn, idxb);
    featTU_k<64,64><<<dim3(1,256),256,0,stream>>>(hs + 0, 512, th[1], ph[1], T, U);
    gather2_k<64><<<BB*NN/4,256,0,stream>>>(T, U, idxb, hs + 64);

    // ---- layer 2: h=hs[:,64:128] (D=64) -> O=128 at ch 128
    transpose_k<64><<<dim3(16,1,16),256,0,stream>>>(hs + 64, hT);
    sqnormT_k<64><<<64,256,0,stream>>>(hT, sqn);
    knn3_k<64><<<dim3(64,16),256,0,stream>>>(hT, sqn, idxb);
    featTU_k<64,128><<<dim3(2,256),256,0,stream>>>(hs + 64, 512, th[2], ph[2], T, U);
    gather2_k<128><<<BB*NN/2,256,0,stream>>>(T, U, idxb, hs + 128);

    // ---- layer 3: h=hs[:,128:256] (D=128) -> O=256 at ch 256
    transpose_k<128><<<dim3(16,2,16),256,0,stream>>>(hs + 128, hT);
    sqnormT_k<128><<<64,256,0,stream>>>(hT, sqn);
    knn3_k<128><<<dim3(64,16),256,0,stream>>>(hT, sqn, idxb);
    featTU_k<128,256><<<dim3(4,256),256,0,stream>>>(hs + 128, 512, th[3], ph[3], T, U);
    gather2_k<256><<<BB*NN,256,0,stream>>>(T, U, idxb, hs + 256);

    // ---- casts (U dead now; wbf corner of T is untouched by pmax/colsum/pooled/z0/z1)
    cast_hs_k<<<4096,256,0,stream>>>(hs, hsbf);
    cast_w_k<<<256,256,0,stream>>>(proj_w, wbf);

    // ---- projection + pooling (max via bf16 MFMA GEMM; mean via fp32 colsum @ w)
    proj3_k<<<1024,256,0,stream>>>(hsbf, wbf, pmax);
    colsum_k<<<32,256,0,stream>>>(hs, colsum);
    pool_final2_k<<<64,256,0,stream>>>(pmax, colsum, proj_w, proj_b, pooled);

    // ---- head
    head_bn_k<2048><<<512,256,0,stream>>>(pooled, emb0_w, emb0_b, bn0_g, bn0_b, z0, 512);
    head_bn_k<512><<<256,256,0,stream>>>(z0, emb1_w, emb1_b, bn1_g, bn1_b, z1, 256);
    head_out_k<<<40,256,0,stream>>>(z1, out_w, out_b, outp);
}

// Round 10
// 988.857 us; speedup vs baseline: 1.2111x; 1.0414x over previous
//
#include <hip/hip_runtime.h>
#include <hip/hip_bf16.h>

#define BB 16
#define NN 1024
#define KNN 20

typedef __attribute__((ext_vector_type(8))) short bf16x8;   // 8 bf16 (4 VGPRs)
typedef __attribute__((ext_vector_type(4))) float f32x4;

__device__ __forceinline__ unsigned short f2b(float f){
    __hip_bfloat16 h = __float2bfloat16(f);
    return *(unsigned short*)&h;
}

// ---------------- fallback: encode ws_size into output if workspace too small ----------------
__global__ void fallback_k(float* __restrict__ out, int n, float c){
    int i = blockIdx.x*256 + threadIdx.x;
    if(i < n) out[i] = c;
}

// ---------------- transpose x [16,1024,3] -> hT [16][3][1024] ----------------
__global__ void transpose3_k(const float* __restrict__ x, float* __restrict__ hT){
    int i = blockIdx.x*256 + threadIdx.x;
    if(i < BB*NN){
        int b = i >> 10, n = i & 1023;
        #pragma unroll
        for(int d=0; d<3; d++)
            hT[((size_t)b*3 + d)*NN + n] = x[(size_t)i*3 + d];
    }
}

// ---------------- transpose hs slice [16,1024,D @stride512] -> hT [16][D][1024] ----------------
template<int D>
__global__ __launch_bounds__(256) void transpose_k(const float* __restrict__ src,
                                                   float* __restrict__ hT){
    int nt = blockIdx.x, ct = blockIdx.y, b = blockIdx.z;
    int tid = threadIdx.x;
    __shared__ float tile[64][65];
    int n0 = nt*64, c0 = ct*64;
    for(int l=tid; l<64*64; l+=256){
        int r = l>>6, c = l&63;
        tile[r][c] = src[(size_t)(b*NN + n0 + r)*512 + c0 + c];
    }
    __syncthreads();
    for(int l=tid; l<64*64; l+=256){
        int d = l>>6, n = l&63;
        hT[((size_t)b*D + c0 + d)*NN + n0 + n] = tile[n][d];
    }
}

// ---------------- squared norms from hT (coalesced; fma chain order matches knn4_k) ----------------
template<int D>
__global__ void sqnormT_k(const float* __restrict__ hT, float* __restrict__ sqn){
    int i = blockIdx.x*256 + threadIdx.x;
    if(i < BB*NN){
        int b = i >> 10, n = i & 1023;
        const float* p = hT + (size_t)b*D*NN + n;
        float s = 0.f;
        for(int d=0; d<D; d++){ float v = p[(size_t)d*NN]; s = fmaf(v, v, s); }
        sqn[i] = s;
    }
}

// ---------------- fused dist-GEMM + top-20, all-register; 8 rows/block (2 per wave) ----------------
// 2048 blocks -> 32 waves/CU (full occupancy) to hide L2 load latency.
// Diagonal exactly 0: same ascending-d fma chain as sqnormT_k; (sa+sq)-2*acc ordering.
template<int D>
__global__ __launch_bounds__(256) void knn4_k(const float* __restrict__ hT,
                                              const float* __restrict__ sqn,
                                              int* __restrict__ idx){
    const int b    = blockIdx.y;
    const int n0   = blockIdx.x * 8;
    const int tid  = threadIdx.x;
    const int lane = tid & 63;
    const int wv   = tid >> 6;

    __shared__ float rowsA[D*8];      // [d][8 rows]
    __shared__ float sqnA[8];

    const float* hTb = hT + (size_t)b*D*NN;
    for(int l=tid; l<8*D; l+=256){
        int d = l >> 3, r = l & 7;
        rowsA[l] = hTb[(size_t)d*NN + n0 + r];
    }
    if(tid < 8) sqnA[tid] = sqn[b*NN + n0 + tid];
    __syncthreads();

    const float4* B4 = (const float4*)hTb;
    float4 acc[2][4];                  // [row r][j]
    #pragma unroll
    for(int r=0;r<2;r++)
        #pragma unroll
        for(int j=0;j<4;j++) acc[r][j] = make_float4(0.f,0.f,0.f,0.f);

    #pragma unroll 2
    for(int d=0; d<D; d++){
        float2 a2 = *(const float2*)&rowsA[d*8 + wv*2];
        float4 bv[4];
        #pragma unroll
        for(int j=0;j<4;j++) bv[j] = B4[d*256 + 64*j + lane];
        float ar[2] = {a2.x, a2.y};
        #pragma unroll
        for(int r=0;r<2;r++)
            #pragma unroll
            for(int j=0;j<4;j++){
                acc[r][j].x = fmaf(ar[r], bv[j].x, acc[r][j].x);
                acc[r][j].y = fmaf(ar[r], bv[j].y, acc[r][j].y);
                acc[r][j].z = fmaf(ar[r], bv[j].z, acc[r][j].z);
                acc[r][j].w = fmaf(ar[r], bv[j].w, acc[r][j].w);
            }
    }

    float4 sq[4];
    #pragma unroll
    for(int j=0;j<4;j++) sq[j] = ((const float4*)(sqn + b*NN))[64*j + lane];

    const float FMAXV = 3.402823466e38f;
    for(int r=0;r<2;r++){
        float sa = sqnA[wv*2 + r];
        float v[16];
        #pragma unroll
        for(int j=0;j<4;j++){
            v[4*j+0] = sa + sq[j].x - 2.f*acc[r][j].x;
            v[4*j+1] = sa + sq[j].y - 2.f*acc[r][j].y;
            v[4*j+2] = sa + sq[j].z - 2.f*acc[r][j].z;
            v[4*j+3] = sa + sq[j].w - 2.f*acc[r][j].w;
        }
        // top-20; ties -> lowest index (matches lax.top_k stability)
        int* out = idx + ((size_t)b*NN + n0 + wv*2 + r)*KNN;
        for(int t=0;t<KNN;t++){
            float bvv = FMAXV; int bi = 0x7fffffff;
            #pragma unroll
            for(int q=0;q<16;q++){
                if(v[q] < bvv){ bvv = v[q]; bi = 4*(lane + 64*(q>>2)) + (q&3); }
            }
            #pragma unroll
            for(int off=32; off>0; off>>=1){
                float ov = __shfl_xor(bvv, off);
                int   oi = __shfl_xor(bi, off);
                if(ov < bvv || (ov == bvv && oi < bi)){ bvv = ov; bi = oi; }
            }
            if(lane == 0) out[t] = bi;
            int ol = (bi >> 2) & 63;
            if(lane == ol){
                int q = ((bi >> 8) << 2) | (bi & 3);
                v[q] = FMAXV;
            }
        }
    }
}

// ---------------- tiled dual GEMM: T = h@theta^T ; U = h@(phi-theta)^T ----------------
template<int D, int O>
__global__ __launch_bounds__(256) void featTU_k(const float* __restrict__ h, int S,
                                                const float* __restrict__ th,
                                                const float* __restrict__ ph,
                                                float* __restrict__ T, float* __restrict__ U){
    int ot = blockIdx.x, nt = blockIdx.y;
    int tid = threadIdx.x, tx = tid & 15, ty = tid >> 4;
    __shared__ float As[64][33];
    __shared__ float Wt[64][33];
    __shared__ float Wp[64][33];
    float acct[4][4] = {};
    float accp[4][4] = {};
    for(int kk=0; kk<D; kk+=32){
        for(int l=tid; l<64*32; l+=256){
            int r = l>>5, c = l&31, d = kk + c;
            As[r][c] = (d < D) ? h[(size_t)(nt*64+r)*S + d] : 0.f;
            Wt[r][c] = (d < D) ? th[(size_t)(ot*64+r)*D + d] : 0.f;
            Wp[r][c] = (d < D) ? ph[(size_t)(ot*64+r)*D + d] : 0.f;
        }
        __syncthreads();
        #pragma unroll
        for(int k=0;k<32;k++){
            float a[4], bt[4], bp[4];
            #pragma unroll
            for(int i=0;i<4;i++) a[i]  = As[ty+16*i][k];
            #pragma unroll
            for(int j=0;j<4;j++){ bt[j] = Wt[tx+16*j][k]; bp[j] = Wp[tx+16*j][k]; }
            #pragma unroll
            for(int i=0;i<4;i++)
                #pragma unroll
                for(int j=0;j<4;j++){
                    acct[i][j] = fmaf(a[i], bt[j], acct[i][j]);
                    accp[i][j] = fmaf(a[i], bp[j], accp[i][j]);
                }
        }
        __syncthreads();
    }
    #pragma unroll
    for(int i=0;i<4;i++){
        int rw = nt*64 + ty + 16*i;
        #pragma unroll
        for(int j=0;j<4;j++){
            int o = ot*64 + tx + 16*j;
            T[(size_t)rw*O + o] = acct[i][j];
            U[(size_t)rw*O + o] = accp[i][j] - acct[i][j];
        }
    }
}

// ---------------- gather 20 neighbors of T, max, + U, leaky ----------------
template<int O>
__global__ __launch_bounds__(256) void gather2_k(const float* __restrict__ T, const float* __restrict__ U,
                                                 const int* __restrict__ idx, float* __restrict__ outp){
    constexpr int P = 256 / O;           // points per block
    int bn0 = blockIdx.x * P;
    int tid = threadIdx.x;
    int p = tid / O, o = tid % O;
    int bn = bn0 + p;
    int b  = bn >> 10;
    __shared__ int nb[P*KNN];
    if(tid < P*KNN){
        int pp = tid / KNN, k = tid % KNN;
        nb[pp*KNN + k] = idx[(size_t)(bn0+pp)*KNN + k] & (NN-1);  // mask: never faults
    }
    __syncthreads();
    const float* Tb = T + (size_t)b*NN*O;
    float m = -3.402823466e38f;
    #pragma unroll
    for(int k=0;k<KNN;k++) m = fmaxf(m, Tb[(size_t)nb[p*KNN+k]*O + o]);
    float v = m + U[(size_t)bn*O + o];
    v = (v > 0.f) ? v : 0.2f*v;
    outp[(size_t)bn*512 + o] = v;
}

// ---------------- cast hs [16384,512] f32 -> bf16 ----------------
__global__ __launch_bounds__(256) void cast_hs_k(const float* __restrict__ hs, unsigned short* __restrict__ hb){
    int i = blockIdx.x*256 + threadIdx.x;       // i indexes groups of 8
    const float4* in4 = (const float4*)hs;
    float4 a = in4[2*i], c = in4[2*i+1];
    unsigned short t[8];
    t[0]=f2b(a.x); t[1]=f2b(a.y); t[2]=f2b(a.z); t[3]=f2b(a.w);
    t[4]=f2b(c.x); t[5]=f2b(c.y); t[6]=f2b(c.z); t[7]=f2b(c.w);
    *(ulonglong2*)&hb[8*i] = *(ulonglong2*)t;
}

// ---------------- cast proj_w [1024,512] f32 -> bf16 ----------------
__global__ __launch_bounds__(256) void cast_w_k(const float* __restrict__ w, unsigned short* __restrict__ wb){
    int i = blockIdx.x*256 + threadIdx.x;
    const float4* in4 = (const float4*)w;
    float4 a = in4[2*i], c = in4[2*i+1];
    unsigned short t[8];
    t[0]=f2b(a.x); t[1]=f2b(a.y); t[2]=f2b(a.z); t[3]=f2b(a.w);
    t[4]=f2b(c.x); t[5]=f2b(c.y); t[6]=f2b(c.z); t[7]=f2b(c.w);
    *(ulonglong2*)&wb[8*i] = *(ulonglong2*)t;
}

// ---------------- projection GEMM via bf16 MFMA: 128x128 tile, max-pool epilogue ----------------
// A[m=lane&15][k=quad*8+j] ; B[n=lane&15][k=quad*8+j] (w stored [n][k]) ;
// D: row=quad*4+reg, col=lane&15  (guide m89/m120 verified layouts).
__global__ __launch_bounds__(256) void proj3_k(const unsigned short* __restrict__ hsb,
                                               const unsigned short* __restrict__ wb,
                                               float* __restrict__ pmax){
    int bi = blockIdx.x;
    int ot = bi >> 7;             // col tile (0..7) in high bits -> A-tile sharers on same XCD
    int nb = bi & 127;
    int b  = nb >> 3, nt = nb & 7;
    int tid = threadIdx.x, lane = tid & 63, wv = tid >> 6;
    int quad = lane >> 4, m = lane & 15;

    __shared__ __align__(16) unsigned short Ab[128*40];   // row stride 40 bf16 = 80 B
    __shared__ __align__(16) unsigned short Bb[128*40];

    f32x4 acc[8][2] = {};
    const unsigned short* ha = hsb + ((size_t)(b*NN + nt*128))*512;
    const unsigned short* wa = wb + (size_t)ot*128*512;

    for(int kk=0; kk<512; kk+=32){
        __syncthreads();
        #pragma unroll
        for(int q=0; q<2; q++){
            int idx = tid + 256*q;          // 512 segs: r=idx>>2 (128 rows), sg=idx&3 (8 bf16 each)
            int r = idx >> 2, sg = idx & 3;
            ulonglong2 va = *(const ulonglong2*)&ha[(size_t)r*512 + kk + sg*8];
            ulonglong2 vw = *(const ulonglong2*)&wa[(size_t)r*512 + kk + sg*8];
            *(ulonglong2*)&Ab[r*40 + sg*8] = va;
            *(ulonglong2*)&Bb[r*40 + sg*8] = vw;
        }
        __syncthreads();
        bf16x8 bf0 = *(bf16x8*)&Bb[(wv*32 + m)*40 + quad*8];
        bf16x8 bf1 = *(bf16x8*)&Bb[(wv*32 + 16 + m)*40 + quad*8];
        #pragma unroll
        for(int rt=0; rt<8; rt++){
            bf16x8 af = *(bf16x8*)&Ab[(rt*16 + m)*40 + quad*8];
            acc[rt][0] = __builtin_amdgcn_mfma_f32_16x16x32_bf16(af, bf0, acc[rt][0], 0,0,0);
            acc[rt][1] = __builtin_amdgcn_mfma_f32_16x16x32_bf16(af, bf1, acc[rt][1], 0,0,0);
        }
    }

    // column max over the 128 rows of this tile
    #pragma unroll
    for(int ct=0; ct<2; ct++){
        float mx = acc[0][ct][0];
        #pragma unroll
        for(int rt=0; rt<8; rt++)
            #pragma unroll
            for(int r=0; r<4; r++) mx = fmaxf(mx, acc[rt][ct][r]);
        mx = fmaxf(mx, __shfl_xor(mx, 16));     // combine quads (rows quad*4+r)
        mx = fmaxf(mx, __shfl_xor(mx, 32));
        if(quad == 0)
            pmax[((size_t)b*8 + nt)*1024 + ot*128 + wv*32 + ct*16 + m] = mx;
    }
}

// ---------------- column sums of hs: colsum[16][512] (for algebraic mean-pool, fp32) ----------------
__global__ void colsum_k(const float* __restrict__ hs, float* __restrict__ colsum){
    int i = blockIdx.x*256 + threadIdx.x;   // b*512 + c
    if(i >= BB*512) return;
    int b = i >> 9, c = i & 511;
    const float* p = hs + (size_t)b*NN*512 + c;
    float s = 0.f;
    for(int n=0;n<NN;n++) s += p[(size_t)n*512];
    colsum[i] = s;
}

// ---------------- combine: max over 8 tiles; mean = colsum@w/1024 (fp32); + bias ----------------
__global__ __launch_bounds__(256) void pool_final2_k(const float* __restrict__ pmax,
                                                     const float* __restrict__ colsum,
                                                     const float* __restrict__ w,
                                                     const float* __restrict__ pb,
                                                     float* __restrict__ pooled){
    int i = blockIdx.x*256 + threadIdx.x;   // b*1024 + o (block covers one b)
    int b = i >> 10, o = i & 1023;
    __shared__ float cs[512];
    for(int l=threadIdx.x; l<512; l+=256) cs[l] = colsum[b*512 + l];
    __syncthreads();
    float m = -3.402823466e38f;
    #pragma unroll
    for(int t=0;t<8;t++) m = fmaxf(m, pmax[((size_t)b*8 + t)*1024 + o]);
    float s = 0.f;
    const float4* w4 = (const float4*)(w + (size_t)o*512);
    const float4* c4 = (const float4*)cs;
    for(int d=0; d<128; d++){
        float4 wv = w4[d]; float4 cv = c4[d];
        s = fmaf(cv.x, wv.x, s); s = fmaf(cv.y, wv.y, s);
        s = fmaf(cv.z, wv.z, s); s = fmaf(cv.w, wv.w, s);
    }
    float bias = pb[o];
    pooled[b*2048 + o]        = m + bias;
    pooled[b*2048 + 1024 + o] = s * (1.f/1024.f) + bias;
}

// ---------------- head FC + BatchNorm(batch of 16) + leaky; one block per feature ----------------
template<int IN>
__global__ __launch_bounds__(256) void head_bn_k(const float* __restrict__ in, const float* __restrict__ w,
                                                 const float* __restrict__ bias, const float* __restrict__ g,
                                                 const float* __restrict__ bt, float* __restrict__ out, int OUT){
    int o = blockIdx.x;
    int tid = threadIdx.x, bb = tid >> 4, s = tid & 15;
    const float* ir = in + (size_t)bb*IN;
    const float* wr = w  + (size_t)o*IN;
    float acc = 0.f;
    for(int d=s; d<IN; d+=16) acc = fmaf(ir[d], wr[d], acc);
    #pragma unroll
    for(int off=8; off>0; off>>=1) acc += __shfl_xor(acc, off);
    __shared__ float vals[16];
    __shared__ float stats[2];
    if(s == 0) vals[bb] = acc + bias[o];
    __syncthreads();
    if(tid == 0){
        float mu = 0.f;
        for(int q=0;q<16;q++) mu += vals[q];
        mu *= (1.f/16.f);
        float var = 0.f;
        for(int q=0;q<16;q++){ float d = vals[q]-mu; var = fmaf(d,d,var); }
        var *= (1.f/16.f);
        stats[0] = mu; stats[1] = rsqrtf(var + 1e-5f);
    }
    __syncthreads();
    if(s == 0){
        float v = (vals[bb]-stats[0])*stats[1]*g[o] + bt[o];
        v = (v > 0.f) ? v : 0.2f*v;
        out[(size_t)bb*OUT + o] = v;
    }
}

// ---------------- final linear -> f32 out [16,40] ----------------
__global__ __launch_bounds__(256) void head_out_k(const float* __restrict__ in, const float* __restrict__ w,
                                                  const float* __restrict__ bias, float* __restrict__ out){
    int o = blockIdx.x;   // 40
    int tid = threadIdx.x, bb = tid >> 4, s = tid & 15;
    const float* ir = in + (size_t)bb*256;
    float acc = 0.f;
    for(int d=s; d<256; d+=16) acc = fmaf(ir[d], w[o*256+d], acc);
    #pragma unroll
    for(int off=8; off>0; off>>=1) acc += __shfl_xor(acc, off);
    if(s == 0) out[bb*40 + o] = acc + bias[o];
}

extern "C" void kernel_launch(void* const* d_in, const int* in_sizes, int n_in,
                              void* d_out, int out_size, void* d_ws, size_t ws_size,
                              hipStream_t stream) {
    const float* x       = (const float*)d_in[0];
    const float* th[4]   = {(const float*)d_in[1], (const float*)d_in[3], (const float*)d_in[5], (const float*)d_in[7]};
    const float* ph[4]   = {(const float*)d_in[2], (const float*)d_in[4], (const float*)d_in[6], (const float*)d_in[8]};
    const float* proj_w  = (const float*)d_in[9];
    const float* proj_b  = (const float*)d_in[10];
    const float* emb0_w  = (const float*)d_in[11];
    const float* emb0_b  = (const float*)d_in[12];
    const float* bn0_g   = (const float*)d_in[13];
    const float* bn0_b   = (const float*)d_in[14];
    const float* emb1_w  = (const float*)d_in[15];
    const float* emb1_b  = (const float*)d_in[16];
    const float* bn1_g   = (const float*)d_in[17];
    const float* bn1_b   = (const float*)d_in[18];
    const float* out_w   = (const float*)d_in[19];
    const float* out_b   = (const float*)d_in[20];
    float* outp = (float*)d_out;

    // workspace layout (float elements) — unchanged (guard passed at 68.5 MB)
    const size_t OFF_HS  = 0;                       // 16384 x 512 = 8,388,608
    const size_t OFF_T   = 8388608;                 // 16384 x 256 = 4,194,304
    const size_t OFF_U   = 12582912;                // 16384 x 256 = 4,194,304
    const size_t OFF_SQN = 16777216;                // 16384
    const size_t OFF_IDX = 16793600;                // 16384 x 20 ints = 327,680
    const size_t REQ_FL  = 17121280;
    const size_t REQ     = REQ_FL * 4;              // 68,485,120 bytes

    if(ws_size < REQ){
        fallback_k<<<(out_size+255)/256, 256, 0, stream>>>(outp, out_size, (float)((double)ws_size*1e-6));
        return;
    }

    float* Wf   = (float*)d_ws;
    float* hs   = Wf + OFF_HS;
    float* T    = Wf + OFF_T;
    float* U    = Wf + OFF_U;
    float* sqn  = Wf + OFF_SQN;
    int*   idxb = (int*)(Wf + OFF_IDX);
    // hT aliases T region (max 16x128x1024 = 8 MB <= 16 MB); hT dead before featTU writes T
    float* hT   = T;
    // post-layer aliases (all dead regions by then):
    float* pmax   = T;                                  // 16*8*1024 = 131,072 fl
    float* colsum = T + 131072;                         // 8,192 fl
    float* pooled = T + 147456;                         // 32,768 fl
    float* z0     = T + 180224;
    float* z1     = T + 188416;
    unsigned short* wbf  = (unsigned short*)(T + 200704);   // 524,288 bf16 (inside T region)
    unsigned short* hsbf = (unsigned short*)U;              // U region (dead after layer 3)

    // ---- layer 0: h=x (S=3,D=3) -> O=64 at hs ch 0
    transpose3_k<<<64,256,0,stream>>>(x, hT);
    sqnormT_k<3><<<64,256,0,stream>>>(hT, sqn);
    knn4_k<3><<<dim3(128,16),256,0,stream>>>(hT, sqn, idxb);
    featTU_k<3,64><<<dim3(1,256),256,0,stream>>>(x, 3, th[0], ph[0], T, U);
    gather2_k<64><<<BB*NN/4,256,0,stream>>>(T, U, idxb, hs + 0);

    // ---- layer 1: h=hs[:,0:64] (S=512,D=64) -> O=64 at ch 64
    transpose_k<64><<<dim3(16,1,16),256,0,stream>>>(hs + 0, hT);
    sqnormT_k<64><<<64,256,0,stream>>>(hT, sqn);
    knn4_k<64><<<dim3(128,16),256,0,stream>>>(hT, sqn, idxb);
    featTU_k<64,64><<<dim3(1,256),256,0,stream>>>(hs + 0, 512, th[1], ph[1], T, U);
    gather2_k<64><<<BB*NN/4,256,0,stream>>>(T, U, idxb, hs + 64);

    // ---- layer 2: h=hs[:,64:128] (D=64) -> O=128 at ch 128
    transpose_k<64><<<dim3(16,1,16),256,0,stream>>>(hs + 64, hT);
    sqnormT_k<64><<<64,256,0,stream>>>(hT, sqn);
    knn4_k<64><<<dim3(128,16),256,0,stream>>>(hT, sqn, idxb);
    featTU_k<64,128><<<dim3(2,256),256,0,stream>>>(hs + 64, 512, th[2], ph[2], T, U);
    gather2_k<128><<<BB*NN/2,256,0,stream>>>(T, U, idxb, hs + 128);

    // ---- layer 3: h=hs[:,128:256] (D=128) -> O=256 at ch 256
    transpose_k<128><<<dim3(16,2,16),256,0,stream>>>(hs + 128, hT);
    sqnormT_k<128><<<64,256,0,stream>>>(hT, sqn);
    knn4_k<128><<<dim3(128,16),256,0,stream>>>(hT, sqn, idxb);
    featTU_k<128,256><<<dim3(4,256),256,0,stream>>>(hs + 128, 512, th[3], ph[3], T, U);
    gather2_k<256><<<BB*NN,256,0,stream>>>(T, U, idxb, hs + 256);

    // ---- casts (U dead now; wbf corner of T untouched by pmax/colsum/pooled/z0/z1)
    cast_hs_k<<<4096,256,0,stream>>>(hs, hsbf);
    cast_w_k<<<256,256,0,stream>>>(proj_w, wbf);

    // ---- projection + pooling (max via bf16 MFMA GEMM; mean via fp32 colsum @ w)
    proj3_k<<<1024,256,0,stream>>>(hsbf, wbf, pmax);
    colsum_k<<<32,256,0,stream>>>(hs, colsum);
    pool_final2_k<<<64,256,0,stream>>>(pmax, colsum, proj_w, proj_b, pooled);

    // ---- head
    head_bn_k<2048><<<512,256,0,stream>>>(pooled, emb0_w, emb0_b, bn0_g, bn0_b, z0, 512);
    head_bn_k<512><<<256,256,0,stream>>>(z0, emb1_w, emb1_b, bn1_g, bn1_b, z1, 256);
    head_out_k<<<40,256,0,stream>>>(z1, out_w, out_b, outp);
}

// Round 11
// 954.265 us; speedup vs baseline: 1.2550x; 1.0362x over previous
//
#include <hip/hip_runtime.h>
#include <hip/hip_bf16.h>

#define BB 16
#define NN 1024
#define KNN 20

typedef __attribute__((ext_vector_type(8))) short bf16x8;   // 8 bf16 (4 VGPRs)
typedef __attribute__((ext_vector_type(4))) float f32x4;

__device__ __forceinline__ unsigned short f2b(float f){
    __hip_bfloat16 h = __float2bfloat16(f);
    return *(unsigned short*)&h;
}

// ---------------- fallback: encode ws_size into output if workspace too small ----------------
__global__ void fallback_k(float* __restrict__ out, int n, float c){
    int i = blockIdx.x*256 + threadIdx.x;
    if(i < n) out[i] = c;
}

// ---------------- transpose x [16,1024,3] -> hT [16][3][1024] ----------------
__global__ void transpose3_k(const float* __restrict__ x, float* __restrict__ hT){
    int i = blockIdx.x*256 + threadIdx.x;
    if(i < BB*NN){
        int b = i >> 10, n = i & 1023;
        #pragma unroll
        for(int d=0; d<3; d++)
            hT[((size_t)b*3 + d)*NN + n] = x[(size_t)i*3 + d];
    }
}

// ---------------- transpose hs slice [16,1024,D @stride512] -> hT [16][D][1024] ----------------
template<int D>
__global__ __launch_bounds__(256) void transpose_k(const float* __restrict__ src,
                                                   float* __restrict__ hT){
    int nt = blockIdx.x, ct = blockIdx.y, b = blockIdx.z;
    int tid = threadIdx.x;
    __shared__ float tile[64][65];
    int n0 = nt*64, c0 = ct*64;
    for(int l=tid; l<64*64; l+=256){
        int r = l>>6, c = l&63;
        tile[r][c] = src[(size_t)(b*NN + n0 + r)*512 + c0 + c];
    }
    __syncthreads();
    for(int l=tid; l<64*64; l+=256){
        int d = l>>6, n = l&63;
        hT[((size_t)b*D + c0 + d)*NN + n0 + n] = tile[n][d];
    }
}

// ---------------- squared norms from hT (coalesced; fma chain order matches knn5_k) ----------------
template<int D>
__global__ void sqnormT_k(const float* __restrict__ hT, float* __restrict__ sqn){
    int i = blockIdx.x*256 + threadIdx.x;
    if(i < BB*NN){
        int b = i >> 10, n = i & 1023;
        const float* p = hT + (size_t)b*D*NN + n;
        float s = 0.f;
        for(int d=0; d<D; d++){ float v = p[(size_t)d*NN]; s = fmaf(v, v, s); }
        sqn[i] = s;
    }
}

// ---------------- fused dist-GEMM + top-20; wave-owned candidate slices (zero redundant loads) ----
// Block: 8 rows, 4 waves. Wave w owns candidates [w*256, w*256+256) for ALL 8 rows:
// per d: 1 distinct float4 B-load/lane + 2 broadcast ds_read_b128 + 32 FMA.
// Dist values round-trip a 32KB LDS buffer into the old per-lane v[16] layout -> topk bit-identical.
// Diagonal exactly 0: same ascending-d fma chain as sqnormT_k; (sa+sq)-2*acc ordering.
template<int D>
__global__ __launch_bounds__(256) void knn5_k(const float* __restrict__ hT,
                                              const float* __restrict__ sqn,
                                              int* __restrict__ idx){
    const int b    = blockIdx.y;
    const int n0   = blockIdx.x * 8;
    const int tid  = threadIdx.x;
    const int lane = tid & 63;
    const int wv   = tid >> 6;

    __shared__ float rowsA[D*8];          // [d][8 rows]
    __shared__ float sqnA[8];
    __shared__ float4 distb4[8*256];      // 32 KB: [row][candidate/4]

    const float* hTb = hT + (size_t)b*D*NN;
    for(int l=tid; l<8*D; l+=256){
        int d = l >> 3, r = l & 7;
        rowsA[l] = hTb[(size_t)d*NN + n0 + r];
    }
    if(tid < 8) sqnA[tid] = sqn[b*NN + n0 + tid];
    __syncthreads();

    const int c4 = wv*64 + lane;          // this thread's float4 candidate index (0..255)
    const float4* B4 = (const float4*)hTb;
    float4 acc[8];
    #pragma unroll
    for(int r=0;r<8;r++) acc[r] = make_float4(0.f,0.f,0.f,0.f);

    #pragma unroll 4
    for(int d=0; d<D; d++){
        float4 bv = B4[d*256 + c4];
        float4 a0 = *(const float4*)&rowsA[d*8];      // broadcast
        float4 a1 = *(const float4*)&rowsA[d*8 + 4];  // broadcast
        float ar[8] = {a0.x,a0.y,a0.z,a0.w,a1.x,a1.y,a1.z,a1.w};
        #pragma unroll
        for(int r=0;r<8;r++){
            acc[r].x = fmaf(ar[r], bv.x, acc[r].x);
            acc[r].y = fmaf(ar[r], bv.y, acc[r].y);
            acc[r].z = fmaf(ar[r], bv.z, acc[r].z);
            acc[r].w = fmaf(ar[r], bv.w, acc[r].w);
        }
    }

    float4 sq4 = ((const float4*)(sqn + b*NN))[c4];
    #pragma unroll
    for(int r=0;r<8;r++){
        float sa = sqnA[r];
        float4 dv;
        dv.x = sa + sq4.x - 2.f*acc[r].x;
        dv.y = sa + sq4.y - 2.f*acc[r].y;
        dv.z = sa + sq4.z - 2.f*acc[r].z;
        dv.w = sa + sq4.w - 2.f*acc[r].w;
        distb4[r*256 + c4] = dv;
    }
    __syncthreads();

    // topk: wave wv handles rows 2wv, 2wv+1; per-lane v[16] layout identical to knn4
    const float FMAXV = 3.402823466e38f;
    for(int rr = 2*wv; rr < 2*wv + 2; rr++){
        float v[16];
        const float4* d4p = &distb4[rr*256];
        #pragma unroll
        for(int q=0;q<4;q++){
            float4 f = d4p[lane + 64*q];
            v[4*q+0]=f.x; v[4*q+1]=f.y; v[4*q+2]=f.z; v[4*q+3]=f.w;
        }
        // top-20; ties -> lowest index (matches lax.top_k stability)
        int* out = idx + ((size_t)b*NN + n0 + rr)*KNN;
        for(int t=0;t<KNN;t++){
            float bvv = FMAXV; int bi = 0x7fffffff;
            #pragma unroll
            for(int q=0;q<16;q++){
                if(v[q] < bvv){ bvv = v[q]; bi = 4*(lane + 64*(q>>2)) + (q&3); }
            }
            #pragma unroll
            for(int off=32; off>0; off>>=1){
                float ov = __shfl_xor(bvv, off);
                int   oi = __shfl_xor(bi, off);
                if(ov < bvv || (ov == bvv && oi < bi)){ bvv = ov; bi = oi; }
            }
            if(lane == 0) out[t] = bi;
            int ol = (bi >> 2) & 63;
            if(lane == ol){
                int q = ((bi >> 8) << 2) | (bi & 3);
                v[q] = FMAXV;
            }
        }
    }
}

// ---------------- tiled dual GEMM: T = h@theta^T ; U = h@(phi-theta)^T ----------------
template<int D, int O>
__global__ __launch_bounds__(256) void featTU_k(const float* __restrict__ h, int S,
                                                const float* __restrict__ th,
                                                const float* __restrict__ ph,
                                                float* __restrict__ T, float* __restrict__ U){
    int ot = blockIdx.x, nt = blockIdx.y;
    int tid = threadIdx.x, tx = tid & 15, ty = tid >> 4;
    __shared__ float As[64][33];
    __shared__ float Wt[64][33];
    __shared__ float Wp[64][33];
    float acct[4][4] = {};
    float accp[4][4] = {};
    for(int kk=0; kk<D; kk+=32){
        for(int l=tid; l<64*32; l+=256){
            int r = l>>5, c = l&31, d = kk + c;
            As[r][c] = (d < D) ? h[(size_t)(nt*64+r)*S + d] : 0.f;
            Wt[r][c] = (d < D) ? th[(size_t)(ot*64+r)*D + d] : 0.f;
            Wp[r][c] = (d < D) ? ph[(size_t)(ot*64+r)*D + d] : 0.f;
        }
        __syncthreads();
        #pragma unroll
        for(int k=0;k<32;k++){
            float a[4], bt[4], bp[4];
            #pragma unroll
            for(int i=0;i<4;i++) a[i]  = As[ty+16*i][k];
            #pragma unroll
            for(int j=0;j<4;j++){ bt[j] = Wt[tx+16*j][k]; bp[j] = Wp[tx+16*j][k]; }
            #pragma unroll
            for(int i=0;i<4;i++)
                #pragma unroll
                for(int j=0;j<4;j++){
                    acct[i][j] = fmaf(a[i], bt[j], acct[i][j]);
                    accp[i][j] = fmaf(a[i], bp[j], accp[i][j]);
                }
        }
        __syncthreads();
    }
    #pragma unroll
    for(int i=0;i<4;i++){
        int rw = nt*64 + ty + 16*i;
        #pragma unroll
        for(int j=0;j<4;j++){
            int o = ot*64 + tx + 16*j;
            T[(size_t)rw*O + o] = acct[i][j];
            U[(size_t)rw*O + o] = accp[i][j] - acct[i][j];
        }
    }
}

// ---------------- gather 20 neighbors of T, max, + U, leaky ----------------
template<int O>
__global__ __launch_bounds__(256) void gather2_k(const float* __restrict__ T, const float* __restrict__ U,
                                                 const int* __restrict__ idx, float* __restrict__ outp){
    constexpr int P = 256 / O;           // points per block
    int bn0 = blockIdx.x * P;
    int tid = threadIdx.x;
    int p = tid / O, o = tid % O;
    int bn = bn0 + p;
    int b  = bn >> 10;
    __shared__ int nb[P*KNN];
    if(tid < P*KNN){
        int pp = tid / KNN, k = tid % KNN;
        nb[pp*KNN + k] = idx[(size_t)(bn0+pp)*KNN + k] & (NN-1);  // mask: never faults
    }
    __syncthreads();
    const float* Tb = T + (size_t)b*NN*O;
    float m = -3.402823466e38f;
    #pragma unroll
    for(int k=0;k<KNN;k++) m = fmaxf(m, Tb[(size_t)nb[p*KNN+k]*O + o]);
    float v = m + U[(size_t)bn*O + o];
    v = (v > 0.f) ? v : 0.2f*v;
    outp[(size_t)bn*512 + o] = v;
}

// ---------------- cast hs [16384,512] f32 -> bf16 ----------------
__global__ __launch_bounds__(256) void cast_hs_k(const float* __restrict__ hs, unsigned short* __restrict__ hb){
    int i = blockIdx.x*256 + threadIdx.x;       // i indexes groups of 8
    const float4* in4 = (const float4*)hs;
    float4 a = in4[2*i], c = in4[2*i+1];
    unsigned short t[8];
    t[0]=f2b(a.x); t[1]=f2b(a.y); t[2]=f2b(a.z); t[3]=f2b(a.w);
    t[4]=f2b(c.x); t[5]=f2b(c.y); t[6]=f2b(c.z); t[7]=f2b(c.w);
    *(ulonglong2*)&hb[8*i] = *(ulonglong2*)t;
}

// ---------------- cast proj_w [1024,512] f32 -> bf16 ----------------
__global__ __launch_bounds__(256) void cast_w_k(const float* __restrict__ w, unsigned short* __restrict__ wb){
    int i = blockIdx.x*256 + threadIdx.x;
    const float4* in4 = (const float4*)w;
    float4 a = in4[2*i], c = in4[2*i+1];
    unsigned short t[8];
    t[0]=f2b(a.x); t[1]=f2b(a.y); t[2]=f2b(a.z); t[3]=f2b(a.w);
    t[4]=f2b(c.x); t[5]=f2b(c.y); t[6]=f2b(c.z); t[7]=f2b(c.w);
    *(ulonglong2*)&wb[8*i] = *(ulonglong2*)t;
}

// ---------------- projection GEMM via bf16 MFMA: 128x128 tile, max-pool epilogue ----------------
__global__ __launch_bounds__(256) void proj3_k(const unsigned short* __restrict__ hsb,
                                               const unsigned short* __restrict__ wb,
                                               float* __restrict__ pmax){
    int bi = blockIdx.x;
    int ot = bi >> 7;             // col tile (0..7) in high bits -> A-tile sharers on same XCD
    int nb = bi & 127;
    int b  = nb >> 3, nt = nb & 7;
    int tid = threadIdx.x, lane = tid & 63, wv = tid >> 6;
    int quad = lane >> 4, m = lane & 15;

    __shared__ __align__(16) unsigned short Ab[128*40];   // row stride 40 bf16 = 80 B
    __shared__ __align__(16) unsigned short Bb[128*40];

    f32x4 acc[8][2] = {};
    const unsigned short* ha = hsb + ((size_t)(b*NN + nt*128))*512;
    const unsigned short* wa = wb + (size_t)ot*128*512;

    for(int kk=0; kk<512; kk+=32){
        __syncthreads();
        #pragma unroll
        for(int q=0; q<2; q++){
            int idx = tid + 256*q;          // 512 segs: r=idx>>2 (128 rows), sg=idx&3 (8 bf16 each)
            int r = idx >> 2, sg = idx & 3;
            ulonglong2 va = *(const ulonglong2*)&ha[(size_t)r*512 + kk + sg*8];
            ulonglong2 vw = *(const ulonglong2*)&wa[(size_t)r*512 + kk + sg*8];
            *(ulonglong2*)&Ab[r*40 + sg*8] = va;
            *(ulonglong2*)&Bb[r*40 + sg*8] = vw;
        }
        __syncthreads();
        bf16x8 bf0 = *(bf16x8*)&Bb[(wv*32 + m)*40 + quad*8];
        bf16x8 bf1 = *(bf16x8*)&Bb[(wv*32 + 16 + m)*40 + quad*8];
        #pragma unroll
        for(int rt=0; rt<8; rt++){
            bf16x8 af = *(bf16x8*)&Ab[(rt*16 + m)*40 + quad*8];
            acc[rt][0] = __builtin_amdgcn_mfma_f32_16x16x32_bf16(af, bf0, acc[rt][0], 0,0,0);
            acc[rt][1] = __builtin_amdgcn_mfma_f32_16x16x32_bf16(af, bf1, acc[rt][1], 0,0,0);
        }
    }

    // column max over the 128 rows of this tile
    #pragma unroll
    for(int ct=0; ct<2; ct++){
        float mx = acc[0][ct][0];
        #pragma unroll
        for(int rt=0; rt<8; rt++)
            #pragma unroll
            for(int r=0; r<4; r++) mx = fmaxf(mx, acc[rt][ct][r]);
        mx = fmaxf(mx, __shfl_xor(mx, 16));     // combine quads (rows quad*4+r)
        mx = fmaxf(mx, __shfl_xor(mx, 32));
        if(quad == 0)
            pmax[((size_t)b*8 + nt)*1024 + ot*128 + wv*32 + ct*16 + m] = mx;
    }
}

// ---------------- column sums of hs: colsum[16][512] (for algebraic mean-pool, fp32) ----------------
__global__ void colsum_k(const float* __restrict__ hs, float* __restrict__ colsum){
    int i = blockIdx.x*256 + threadIdx.x;   // b*512 + c
    if(i >= BB*512) return;
    int b = i >> 9, c = i & 511;
    const float* p = hs + (size_t)b*NN*512 + c;
    float s = 0.f;
    for(int n=0;n<NN;n++) s += p[(size_t)n*512];
    colsum[i] = s;
}

// ---------------- combine: max over 8 tiles; mean = colsum@w/1024 (fp32); + bias ----------------
__global__ __launch_bounds__(256) void pool_final2_k(const float* __restrict__ pmax,
                                                     const float* __restrict__ colsum,
                                                     const float* __restrict__ w,
                                                     const float* __restrict__ pb,
                                                     float* __restrict__ pooled){
    int i = blockIdx.x*256 + threadIdx.x;   // b*1024 + o (block covers one b)
    int b = i >> 10, o = i & 1023;
    __shared__ float cs[512];
    for(int l=threadIdx.x; l<512; l+=256) cs[l] = colsum[b*512 + l];
    __syncthreads();
    float m = -3.402823466e38f;
    #pragma unroll
    for(int t=0;t<8;t++) m = fmaxf(m, pmax[((size_t)b*8 + t)*1024 + o]);
    float s = 0.f;
    const float4* w4 = (const float4*)(w + (size_t)o*512);
    const float4* c4 = (const float4*)cs;
    for(int d=0; d<128; d++){
        float4 wv = w4[d]; float4 cv = c4[d];
        s = fmaf(cv.x, wv.x, s); s = fmaf(cv.y, wv.y, s);
        s = fmaf(cv.z, wv.z, s); s = fmaf(cv.w, wv.w, s);
    }
    float bias = pb[o];
    pooled[b*2048 + o]        = m + bias;
    pooled[b*2048 + 1024 + o] = s * (1.f/1024.f) + bias;
}

// ---------------- head FC + BatchNorm(batch of 16) + leaky; one block per feature ----------------
template<int IN>
__global__ __launch_bounds__(256) void head_bn_k(const float* __restrict__ in, const float* __restrict__ w,
                                                 const float* __restrict__ bias, const float* __restrict__ g,
                                                 const float* __restrict__ bt, float* __restrict__ out, int OUT){
    int o = blockIdx.x;
    int tid = threadIdx.x, bb = tid >> 4, s = tid & 15;
    const float* ir = in + (size_t)bb*IN;
    const float* wr = w  + (size_t)o*IN;
    float acc = 0.f;
    for(int d=s; d<IN; d+=16) acc = fmaf(ir[d], wr[d], acc);
    #pragma unroll
    for(int off=8; off>0; off>>=1) acc += __shfl_xor(acc, off);
    __shared__ float vals[16];
    __shared__ float stats[2];
    if(s == 0) vals[bb] = acc + bias[o];
    __syncthreads();
    if(tid == 0){
        float mu = 0.f;
        for(int q=0;q<16;q++) mu += vals[q];
        mu *= (1.f/16.f);
        float var = 0.f;
        for(int q=0;q<16;q++){ float d = vals[q]-mu; var = fmaf(d,d,var); }
        var *= (1.f/16.f);
        stats[0] = mu; stats[1] = rsqrtf(var + 1e-5f);
    }
    __syncthreads();
    if(s == 0){
        float v = (vals[bb]-stats[0])*stats[1]*g[o] + bt[o];
        v = (v > 0.f) ? v : 0.2f*v;
        out[(size_t)bb*OUT + o] = v;
    }
}

// ---------------- final linear -> f32 out [16,40] ----------------
__global__ __launch_bounds__(256) void head_out_k(const float* __restrict__ in, const float* __restrict__ w,
                                                  const float* __restrict__ bias, float* __restrict__ out){
    int o = blockIdx.x;   // 40
    int tid = threadIdx.x, bb = tid >> 4, s = tid & 15;
    const float* ir = in + (size_t)bb*256;
    float acc = 0.f;
    for(int d=s; d<256; d+=16) acc = fmaf(ir[d], w[o*256+d], acc);
    #pragma unroll
    for(int off=8; off>0; off>>=1) acc += __shfl_xor(acc, off);
    if(s == 0) out[bb*40 + o] = acc + bias[o];
}

extern "C" void kernel_launch(void* const* d_in, const int* in_sizes, int n_in,
                              void* d_out, int out_size, void* d_ws, size_t ws_size,
                              hipStream_t stream) {
    const float* x       = (const float*)d_in[0];
    const float* th[4]   = {(const float*)d_in[1], (const float*)d_in[3], (const float*)d_in[5], (const float*)d_in[7]};
    const float* ph[4]   = {(const float*)d_in[2], (const float*)d_in[4], (const float*)d_in[6], (const float*)d_in[8]};
    const float* proj_w  = (const float*)d_in[9];
    const float* proj_b  = (const float*)d_in[10];
    const float* emb0_w  = (const float*)d_in[11];
    const float* emb0_b  = (const float*)d_in[12];
    const float* bn0_g   = (const float*)d_in[13];
    const float* bn0_b   = (const float*)d_in[14];
    const float* emb1_w  = (const float*)d_in[15];
    const float* emb1_b  = (const float*)d_in[16];
    const float* bn1_g   = (const float*)d_in[17];
    const float* bn1_b   = (const float*)d_in[18];
    const float* out_w   = (const float*)d_in[19];
    const float* out_b   = (const float*)d_in[20];
    float* outp = (float*)d_out;

    // workspace layout (float elements) — unchanged (guard passed at 68.5 MB)
    const size_t OFF_HS  = 0;                       // 16384 x 512 = 8,388,608
    const size_t OFF_T   = 8388608;                 // 16384 x 256 = 4,194,304
    const size_t OFF_U   = 12582912;                // 16384 x 256 = 4,194,304
    const size_t OFF_SQN = 16777216;                // 16384
    const size_t OFF_IDX = 16793600;                // 16384 x 20 ints = 327,680
    const size_t REQ_FL  = 17121280;
    const size_t REQ     = REQ_FL * 4;              // 68,485,120 bytes

    if(ws_size < REQ){
        fallback_k<<<(out_size+255)/256, 256, 0, stream>>>(outp, out_size, (float)((double)ws_size*1e-6));
        return;
    }

    float* Wf   = (float*)d_ws;
    float* hs   = Wf + OFF_HS;
    float* T    = Wf + OFF_T;
    float* U    = Wf + OFF_U;
    float* sqn  = Wf + OFF_SQN;
    int*   idxb = (int*)(Wf + OFF_IDX);
    // hT aliases T region (max 16x128x1024 = 8 MB <= 16 MB); hT dead before featTU writes T
    float* hT   = T;
    // post-layer aliases (all dead regions by then):
    float* pmax   = T;                                  // 16*8*1024 = 131,072 fl
    float* colsum = T + 131072;                         // 8,192 fl
    float* pooled = T + 147456;                         // 32,768 fl
    float* z0     = T + 180224;
    float* z1     = T + 188416;
    unsigned short* wbf  = (unsigned short*)(T + 200704);   // 524,288 bf16 (inside T region)
    unsigned short* hsbf = (unsigned short*)U;              // U region (dead after layer 3)

    // ---- layer 0: h=x (S=3,D=3) -> O=64 at hs ch 0
    transpose3_k<<<64,256,0,stream>>>(x, hT);
    sqnormT_k<3><<<64,256,0,stream>>>(hT, sqn);
    knn5_k<3><<<dim3(128,16),256,0,stream>>>(hT, sqn, idxb);
    featTU_k<3,64><<<dim3(1,256),256,0,stream>>>(x, 3, th[0], ph[0], T, U);
    gather2_k<64><<<BB*NN/4,256,0,stream>>>(T, U, idxb, hs + 0);

    // ---- layer 1: h=hs[:,0:64] (S=512,D=64) -> O=64 at ch 64
    transpose_k<64><<<dim3(16,1,16),256,0,stream>>>(hs + 0, hT);
    sqnormT_k<64><<<64,256,0,stream>>>(hT, sqn);
    knn5_k<64><<<dim3(128,16),256,0,stream>>>(hT, sqn, idxb);
    featTU_k<64,64><<<dim3(1,256),256,0,stream>>>(hs + 0, 512, th[1], ph[1], T, U);
    gather2_k<64><<<BB*NN/4,256,0,stream>>>(T, U, idxb, hs + 64);

    // ---- layer 2: h=hs[:,64:128] (D=64) -> O=128 at ch 128
    transpose_k<64><<<dim3(16,1,16),256,0,stream>>>(hs + 64, hT);
    sqnormT_k<64><<<64,256,0,stream>>>(hT, sqn);
    knn5_k<64><<<dim3(128,16),256,0,stream>>>(hT, sqn, idxb);
    featTU_k<64,128><<<dim3(2,256),256,0,stream>>>(hs + 64, 512, th[2], ph[2], T, U);
    gather2_k<128><<<BB*NN/2,256,0,stream>>>(T, U, idxb, hs + 128);

    // ---- layer 3: h=hs[:,128:256] (D=128) -> O=256 at ch 256
    transpose_k<128><<<dim3(16,2,16),256,0,stream>>>(hs + 128, hT);
    sqnormT_k<128><<<64,256,0,stream>>>(hT, sqn);
    knn5_k<128><<<dim3(128,16),256,0,stream>>>(hT, sqn, idxb);
    featTU_k<128,256><<<dim3(4,256),256,0,stream>>>(hs + 128, 512, th[3], ph[3], T, U);
    gather2_k<256><<<BB*NN,256,0,stream>>>(T, U, idxb, hs + 256);

    // ---- casts (U dead now; wbf corner of T untouched by pmax/colsum/pooled/z0/z1)
    cast_hs_k<<<4096,256,0,stream>>>(hs, hsbf);
    cast_w_k<<<256,256,0,stream>>>(proj_w, wbf);

    // ---- projection + pooling (max via bf16 MFMA GEMM; mean via fp32 colsum @ w)
    proj3_k<<<1024,256,0,stream>>>(hsbf, wbf, pmax);
    colsum_k<<<32,256,0,stream>>>(hs, colsum);
    pool_final2_k<<<64,256,0,stream>>>(pmax, colsum, proj_w, proj_b, pooled);

    // ---- head
    head_bn_k<2048><<<512,256,0,stream>>>(pooled, emb0_w, emb0_b, bn0_g, bn0_b, z0, 512);
    head_bn_k<512><<<256,256,0,stream>>>(z0, emb1_w, emb1_b, bn1_g, bn1_b, z1, 256);
    head_out_k<<<40,256,0,stream>>>(z1, out_w, out_b, outp);
}

// Round 12
// 782.683 us; speedup vs baseline: 1.5301x; 1.2192x over previous
//
#include <hip/hip_runtime.h>
#include <hip/hip_bf16.h>

#define BB 16
#define NN 1024
#define KNN 20

typedef __attribute__((ext_vector_type(8))) short bf16x8;   // 8 bf16 (4 VGPRs)
typedef __attribute__((ext_vector_type(4))) float f32x4;

__device__ __forceinline__ unsigned short f2b(float f){
    __hip_bfloat16 h = __float2bfloat16(f);
    return *(unsigned short*)&h;
}

// ---------------- fallback: encode ws_size into output if workspace too small ----------------
__global__ void fallback_k(float* __restrict__ out, int n, float c){
    int i = blockIdx.x*256 + threadIdx.x;
    if(i < n) out[i] = c;
}

// ---------------- transpose x [16,1024,3] -> hT [16][3][1024] ----------------
__global__ void transpose3_k(const float* __restrict__ x, float* __restrict__ hT){
    int i = blockIdx.x*256 + threadIdx.x;
    if(i < BB*NN){
        int b = i >> 10, n = i & 1023;
        #pragma unroll
        for(int d=0; d<3; d++)
            hT[((size_t)b*3 + d)*NN + n] = x[(size_t)i*3 + d];
    }
}

// ---------------- transpose hs slice [16,1024,D @stride512] -> hT [16][D][1024] ----------------
template<int D>
__global__ __launch_bounds__(256) void transpose_k(const float* __restrict__ src,
                                                   float* __restrict__ hT){
    int nt = blockIdx.x, ct = blockIdx.y, b = blockIdx.z;
    int tid = threadIdx.x;
    __shared__ float tile[64][65];
    int n0 = nt*64, c0 = ct*64;
    for(int l=tid; l<64*64; l+=256){
        int r = l>>6, c = l&63;
        tile[r][c] = src[(size_t)(b*NN + n0 + r)*512 + c0 + c];
    }
    __syncthreads();
    for(int l=tid; l<64*64; l+=256){
        int d = l>>6, n = l&63;
        hT[((size_t)b*D + c0 + d)*NN + n0 + n] = tile[n][d];
    }
}

// ---------------- squared norms from hT (coalesced; fma chain order matches knn6_k) ----------------
template<int D>
__global__ void sqnormT_k(const float* __restrict__ hT, float* __restrict__ sqn){
    int i = blockIdx.x*256 + threadIdx.x;
    if(i < BB*NN){
        int b = i >> 10, n = i & 1023;
        const float* p = hT + (size_t)b*D*NN + n;
        float s = 0.f;
        for(int d=0; d<D; d++){ float v = p[(size_t)d*NN]; s = fmaf(v, v, s); }
        sqn[i] = s;
    }
}

// ---------------- fused dist-GEMM + top-20 (sorted-head selection) ----------------
// GEMM phase identical to round-11 knn5 (bit-identical dist values).
// Top-k: packed monotonic keys (IEEE-flip, low 4 bits = lane-slot q), per-lane bitonic sort,
// then 20x u64 butterfly-min over per-lane sorted heads. Ties -> lowest global index.
template<int D>
__global__ __launch_bounds__(256) void knn6_k(const float* __restrict__ hT,
                                              const float* __restrict__ sqn,
                                              int* __restrict__ idx){
    const int b    = blockIdx.y;
    const int n0   = blockIdx.x * 8;
    const int tid  = threadIdx.x;
    const int lane = tid & 63;
    const int wv   = tid >> 6;

    __shared__ float rowsA[D*8];          // [d][8 rows]
    __shared__ float sqnA[8];
    __shared__ float4 distb4[8*256];      // 32 KB: [row][candidate/4]

    const float* hTb = hT + (size_t)b*D*NN;
    for(int l=tid; l<8*D; l+=256){
        int d = l >> 3, r = l & 7;
        rowsA[l] = hTb[(size_t)d*NN + n0 + r];
    }
    if(tid < 8) sqnA[tid] = sqn[b*NN + n0 + tid];
    __syncthreads();

    const int c4 = wv*64 + lane;          // this thread's float4 candidate index (0..255)
    const float4* B4 = (const float4*)hTb;
    float4 acc[8];
    #pragma unroll
    for(int r=0;r<8;r++) acc[r] = make_float4(0.f,0.f,0.f,0.f);

    #pragma unroll 4
    for(int d=0; d<D; d++){
        float4 bv = B4[d*256 + c4];
        float4 a0 = *(const float4*)&rowsA[d*8];      // broadcast
        float4 a1 = *(const float4*)&rowsA[d*8 + 4];  // broadcast
        float ar[8] = {a0.x,a0.y,a0.z,a0.w,a1.x,a1.y,a1.z,a1.w};
        #pragma unroll
        for(int r=0;r<8;r++){
            acc[r].x = fmaf(ar[r], bv.x, acc[r].x);
            acc[r].y = fmaf(ar[r], bv.y, acc[r].y);
            acc[r].z = fmaf(ar[r], bv.z, acc[r].z);
            acc[r].w = fmaf(ar[r], bv.w, acc[r].w);
        }
    }

    float4 sq4 = ((const float4*)(sqn + b*NN))[c4];
    #pragma unroll
    for(int r=0;r<8;r++){
        float sa = sqnA[r];
        float4 dv;
        dv.x = sa + sq4.x - 2.f*acc[r].x;
        dv.y = sa + sq4.y - 2.f*acc[r].y;
        dv.z = sa + sq4.z - 2.f*acc[r].z;
        dv.w = sa + sq4.w - 2.f*acc[r].w;
        distb4[r*256 + c4] = dv;
    }
    __syncthreads();

    // top-20 per row; wave wv handles rows 2wv, 2wv+1
    for(int rr = 2*wv; rr < 2*wv + 2; rr++){
        // 1) load 16 dists, build monotonic packed keys: flip(dist) with low4 = slot q
        unsigned s[16];
        const float4* d4p = &distb4[rr*256];
        #pragma unroll
        for(int q4=0;q4<4;q4++){
            float4 f = d4p[lane + 64*q4];
            float vv[4] = {f.x, f.y, f.z, f.w};
            #pragma unroll
            for(int c=0;c<4;c++){
                unsigned u = __float_as_uint(vv[c]);
                u ^= (unsigned)((int)u >> 31) | 0x80000000u;   // monotonic float->u32
                s[q4*4+c] = (u & 0xFFFFFFF0u) | (unsigned)(q4*4+c);
            }
        }
        // 2) bitonic sort ascending (fully unrolled, registers only)
        #pragma unroll
        for(int k=2;k<=16;k<<=1){
            #pragma unroll
            for(int j=k>>1;j>0;j>>=1){
                #pragma unroll
                for(int i=0;i<16;i++){
                    int l = i ^ j;
                    if(l > i){
                        unsigned a = s[i], bq = s[l];
                        unsigned lo = a < bq ? a : bq;
                        unsigned hi = a < bq ? bq : a;
                        bool up = ((i & k) == 0);
                        s[i] = up ? lo : hi;
                        s[l] = up ? hi : lo;
                    }
                }
            }
        }
        // 3) head = (key<<32)|globalidx ; 20x butterfly-min + winner shift
        unsigned h0 = s[0];
        int q = h0 & 15;
        unsigned long long cur = ((unsigned long long)h0 << 32)
                               | (unsigned)(4*lane + 256*(q>>2) + (q&3));
        int* out = idx + ((size_t)b*NN + n0 + rr)*KNN;
        for(int t=0;t<KNN;t++){
            unsigned long long w = cur;
            #pragma unroll
            for(int off=32; off>0; off>>=1){
                unsigned long long o = __shfl_xor(w, off);
                if(o < w) w = o;
            }
            if(lane == 0) out[t] = (int)(unsigned)(w & 0xFFFFFFFFu);
            if(w == cur){
                #pragma unroll
                for(int i=0;i<15;i++) s[i] = s[i+1];
                s[15] = 0xFFFFFFFFu;
                unsigned nh = s[0];
                int nq = nh & 15;
                cur = ((unsigned long long)nh << 32)
                    | (unsigned)(4*lane + 256*(nq>>2) + (nq&3));
            }
        }
    }
}

// ---------------- tiled dual GEMM: T = h@theta^T ; U = h@(phi-theta)^T ----------------
template<int D, int O>
__global__ __launch_bounds__(256) void featTU_k(const float* __restrict__ h, int S,
                                                const float* __restrict__ th,
                                                const float* __restrict__ ph,
                                                float* __restrict__ T, float* __restrict__ U){
    int ot = blockIdx.x, nt = blockIdx.y;
    int tid = threadIdx.x, tx = tid & 15, ty = tid >> 4;
    __shared__ float As[64][33];
    __shared__ float Wt[64][33];
    __shared__ float Wp[64][33];
    float acct[4][4] = {};
    float accp[4][4] = {};
    for(int kk=0; kk<D; kk+=32){
        for(int l=tid; l<64*32; l+=256){
            int r = l>>5, c = l&31, d = kk + c;
            As[r][c] = (d < D) ? h[(size_t)(nt*64+r)*S + d] : 0.f;
            Wt[r][c] = (d < D) ? th[(size_t)(ot*64+r)*D + d] : 0.f;
            Wp[r][c] = (d < D) ? ph[(size_t)(ot*64+r)*D + d] : 0.f;
        }
        __syncthreads();
        #pragma unroll
        for(int k=0;k<32;k++){
            float a[4], bt[4], bp[4];
            #pragma unroll
            for(int i=0;i<4;i++) a[i]  = As[ty+16*i][k];
            #pragma unroll
            for(int j=0;j<4;j++){ bt[j] = Wt[tx+16*j][k]; bp[j] = Wp[tx+16*j][k]; }
            #pragma unroll
            for(int i=0;i<4;i++)
                #pragma unroll
                for(int j=0;j<4;j++){
                    acct[i][j] = fmaf(a[i], bt[j], acct[i][j]);
                    accp[i][j] = fmaf(a[i], bp[j], accp[i][j]);
                }
        }
        __syncthreads();
    }
    #pragma unroll
    for(int i=0;i<4;i++){
        int rw = nt*64 + ty + 16*i;
        #pragma unroll
        for(int j=0;j<4;j++){
            int o = ot*64 + tx + 16*j;
            T[(size_t)rw*O + o] = acct[i][j];
            U[(size_t)rw*O + o] = accp[i][j] - acct[i][j];
        }
    }
}

// ---------------- gather 20 neighbors of T, max, + U, leaky ----------------
template<int O>
__global__ __launch_bounds__(256) void gather2_k(const float* __restrict__ T, const float* __restrict__ U,
                                                 const int* __restrict__ idx, float* __restrict__ outp){
    constexpr int P = 256 / O;           // points per block
    int bn0 = blockIdx.x * P;
    int tid = threadIdx.x;
    int p = tid / O, o = tid % O;
    int bn = bn0 + p;
    int b  = bn >> 10;
    __shared__ int nb[P*KNN];
    if(tid < P*KNN){
        int pp = tid / KNN, k = tid % KNN;
        nb[pp*KNN + k] = idx[(size_t)(bn0+pp)*KNN + k] & (NN-1);  // mask: never faults
    }
    __syncthreads();
    const float* Tb = T + (size_t)b*NN*O;
    float m = -3.402823466e38f;
    #pragma unroll
    for(int k=0;k<KNN;k++) m = fmaxf(m, Tb[(size_t)nb[p*KNN+k]*O + o]);
    float v = m + U[(size_t)bn*O + o];
    v = (v > 0.f) ? v : 0.2f*v;
    outp[(size_t)bn*512 + o] = v;
}

// ---------------- cast hs [16384,512] f32 -> bf16 ----------------
__global__ __launch_bounds__(256) void cast_hs_k(const float* __restrict__ hs, unsigned short* __restrict__ hb){
    int i = blockIdx.x*256 + threadIdx.x;       // i indexes groups of 8
    const float4* in4 = (const float4*)hs;
    float4 a = in4[2*i], c = in4[2*i+1];
    unsigned short t[8];
    t[0]=f2b(a.x); t[1]=f2b(a.y); t[2]=f2b(a.z); t[3]=f2b(a.w);
    t[4]=f2b(c.x); t[5]=f2b(c.y); t[6]=f2b(c.z); t[7]=f2b(c.w);
    *(ulonglong2*)&hb[8*i] = *(ulonglong2*)t;
}

// ---------------- cast proj_w [1024,512] f32 -> bf16 ----------------
__global__ __launch_bounds__(256) void cast_w_k(const float* __restrict__ w, unsigned short* __restrict__ wb){
    int i = blockIdx.x*256 + threadIdx.x;
    const float4* in4 = (const float4*)w;
    float4 a = in4[2*i], c = in4[2*i+1];
    unsigned short t[8];
    t[0]=f2b(a.x); t[1]=f2b(a.y); t[2]=f2b(a.z); t[3]=f2b(a.w);
    t[4]=f2b(c.x); t[5]=f2b(c.y); t[6]=f2b(c.z); t[7]=f2b(c.w);
    *(ulonglong2*)&wb[8*i] = *(ulonglong2*)t;
}

// ---------------- projection GEMM via bf16 MFMA: 128x128 tile, max-pool epilogue ----------------
__global__ __launch_bounds__(256) void proj3_k(const unsigned short* __restrict__ hsb,
                                               const unsigned short* __restrict__ wb,
                                               float* __restrict__ pmax){
    int bi = blockIdx.x;
    int ot = bi >> 7;             // col tile (0..7) in high bits -> A-tile sharers on same XCD
    int nb = bi & 127;
    int b  = nb >> 3, nt = nb & 7;
    int tid = threadIdx.x, lane = tid & 63, wv = tid >> 6;
    int quad = lane >> 4, m = lane & 15;

    __shared__ __align__(16) unsigned short Ab[128*40];   // row stride 40 bf16 = 80 B
    __shared__ __align__(16) unsigned short Bb[128*40];

    f32x4 acc[8][2] = {};
    const unsigned short* ha = hsb + ((size_t)(b*NN + nt*128))*512;
    const unsigned short* wa = wb + (size_t)ot*128*512;

    for(int kk=0; kk<512; kk+=32){
        __syncthreads();
        #pragma unroll
        for(int q=0; q<2; q++){
            int idx = tid + 256*q;          // 512 segs: r=idx>>2 (128 rows), sg=idx&3 (8 bf16 each)
            int r = idx >> 2, sg = idx & 3;
            ulonglong2 va = *(const ulonglong2*)&ha[(size_t)r*512 + kk + sg*8];
            ulonglong2 vw = *(const ulonglong2*)&wa[(size_t)r*512 + kk + sg*8];
            *(ulonglong2*)&Ab[r*40 + sg*8] = va;
            *(ulonglong2*)&Bb[r*40 + sg*8] = vw;
        }
        __syncthreads();
        bf16x8 bf0 = *(bf16x8*)&Bb[(wv*32 + m)*40 + quad*8];
        bf16x8 bf1 = *(bf16x8*)&Bb[(wv*32 + 16 + m)*40 + quad*8];
        #pragma unroll
        for(int rt=0; rt<8; rt++){
            bf16x8 af = *(bf16x8*)&Ab[(rt*16 + m)*40 + quad*8];
            acc[rt][0] = __builtin_amdgcn_mfma_f32_16x16x32_bf16(af, bf0, acc[rt][0], 0,0,0);
            acc[rt][1] = __builtin_amdgcn_mfma_f32_16x16x32_bf16(af, bf1, acc[rt][1], 0,0,0);
        }
    }

    // column max over the 128 rows of this tile
    #pragma unroll
    for(int ct=0; ct<2; ct++){
        float mx = acc[0][ct][0];
        #pragma unroll
        for(int rt=0; rt<8; rt++)
            #pragma unroll
            for(int r=0; r<4; r++) mx = fmaxf(mx, acc[rt][ct][r]);
        mx = fmaxf(mx, __shfl_xor(mx, 16));     // combine quads (rows quad*4+r)
        mx = fmaxf(mx, __shfl_xor(mx, 32));
        if(quad == 0)
            pmax[((size_t)b*8 + nt)*1024 + ot*128 + wv*32 + ct*16 + m] = mx;
    }
}

// ---------------- column sums of hs: colsum[16][512] (for algebraic mean-pool, fp32) ----------------
__global__ void colsum_k(const float* __restrict__ hs, float* __restrict__ colsum){
    int i = blockIdx.x*256 + threadIdx.x;   // b*512 + c
    if(i >= BB*512) return;
    int b = i >> 9, c = i & 511;
    const float* p = hs + (size_t)b*NN*512 + c;
    float s = 0.f;
    for(int n=0;n<NN;n++) s += p[(size_t)n*512];
    colsum[i] = s;
}

// ---------------- combine: max over 8 tiles; mean = colsum@w/1024 (fp32); + bias ----------------
__global__ __launch_bounds__(256) void pool_final2_k(const float* __restrict__ pmax,
                                                     const float* __restrict__ colsum,
                                                     const float* __restrict__ w,
                                                     const float* __restrict__ pb,
                                                     float* __restrict__ pooled){
    int i = blockIdx.x*256 + threadIdx.x;   // b*1024 + o (block covers one b)
    int b = i >> 10, o = i & 1023;
    __shared__ float cs[512];
    for(int l=threadIdx.x; l<512; l+=256) cs[l] = colsum[b*512 + l];
    __syncthreads();
    float m = -3.402823466e38f;
    #pragma unroll
    for(int t=0;t<8;t++) m = fmaxf(m, pmax[((size_t)b*8 + t)*1024 + o]);
    float s = 0.f;
    const float4* w4 = (const float4*)(w + (size_t)o*512);
    const float4* c4 = (const float4*)cs;
    for(int d=0; d<128; d++){
        float4 wv = w4[d]; float4 cv = c4[d];
        s = fmaf(cv.x, wv.x, s); s = fmaf(cv.y, wv.y, s);
        s = fmaf(cv.z, wv.z, s); s = fmaf(cv.w, wv.w, s);
    }
    float bias = pb[o];
    pooled[b*2048 + o]        = m + bias;
    pooled[b*2048 + 1024 + o] = s * (1.f/1024.f) + bias;
}

// ---------------- head FC + BatchNorm(batch of 16) + leaky; one block per feature ----------------
template<int IN>
__global__ __launch_bounds__(256) void head_bn_k(const float* __restrict__ in, const float* __restrict__ w,
                                                 const float* __restrict__ bias, const float* __restrict__ g,
                                                 const float* __restrict__ bt, float* __restrict__ out, int OUT){
    int o = blockIdx.x;
    int tid = threadIdx.x, bb = tid >> 4, s = tid & 15;
    const float* ir = in + (size_t)bb*IN;
    const float* wr = w  + (size_t)o*IN;
    float acc = 0.f;
    for(int d=s; d<IN; d+=16) acc = fmaf(ir[d], wr[d], acc);
    #pragma unroll
    for(int off=8; off>0; off>>=1) acc += __shfl_xor(acc, off);
    __shared__ float vals[16];
    __shared__ float stats[2];
    if(s == 0) vals[bb] = acc + bias[o];
    __syncthreads();
    if(tid == 0){
        float mu = 0.f;
        for(int q=0;q<16;q++) mu += vals[q];
        mu *= (1.f/16.f);
        float var = 0.f;
        for(int q=0;q<16;q++){ float d = vals[q]-mu; var = fmaf(d,d,var); }
        var *= (1.f/16.f);
        stats[0] = mu; stats[1] = rsqrtf(var + 1e-5f);
    }
    __syncthreads();
    if(s == 0){
        float v = (vals[bb]-stats[0])*stats[1]*g[o] + bt[o];
        v = (v > 0.f) ? v : 0.2f*v;
        out[(size_t)bb*OUT + o] = v;
    }
}

// ---------------- final linear -> f32 out [16,40] ----------------
__global__ __launch_bounds__(256) void head_out_k(const float* __restrict__ in, const float* __restrict__ w,
                                                  const float* __restrict__ bias, float* __restrict__ out){
    int o = blockIdx.x;   // 40
    int tid = threadIdx.x, bb = tid >> 4, s = tid & 15;
    const float* ir = in + (size_t)bb*256;
    float acc = 0.f;
    for(int d=s; d<256; d+=16) acc = fmaf(ir[d], w[o*256+d], acc);
    #pragma unroll
    for(int off=8; off>0; off>>=1) acc += __shfl_xor(acc, off);
    if(s == 0) out[bb*40 + o] = acc + bias[o];
}

extern "C" void kernel_launch(void* const* d_in, const int* in_sizes, int n_in,
                              void* d_out, int out_size, void* d_ws, size_t ws_size,
                              hipStream_t stream) {
    const float* x       = (const float*)d_in[0];
    const float* th[4]   = {(const float*)d_in[1], (const float*)d_in[3], (const float*)d_in[5], (const float*)d_in[7]};
    const float* ph[4]   = {(const float*)d_in[2], (const float*)d_in[4], (const float*)d_in[6], (const float*)d_in[8]};
    const float* proj_w  = (const float*)d_in[9];
    const float* proj_b  = (const float*)d_in[10];
    const float* emb0_w  = (const float*)d_in[11];
    const float* emb0_b  = (const float*)d_in[12];
    const float* bn0_g   = (const float*)d_in[13];
    const float* bn0_b   = (const float*)d_in[14];
    const float* emb1_w  = (const float*)d_in[15];
    const float* emb1_b  = (const float*)d_in[16];
    const float* bn1_g   = (const float*)d_in[17];
    const float* bn1_b   = (const float*)d_in[18];
    const float* out_w   = (const float*)d_in[19];
    const float* out_b   = (const float*)d_in[20];
    float* outp = (float*)d_out;

    // workspace layout (float elements) — unchanged (guard passed at 68.5 MB)
    const size_t OFF_HS  = 0;                       // 16384 x 512 = 8,388,608
    const size_t OFF_T   = 8388608;                 // 16384 x 256 = 4,194,304
    const size_t OFF_U   = 12582912;                // 16384 x 256 = 4,194,304
    const size_t OFF_SQN = 16777216;                // 16384
    const size_t OFF_IDX = 16793600;                // 16384 x 20 ints = 327,680
    const size_t REQ_FL  = 17121280;
    const size_t REQ     = REQ_FL * 4;              // 68,485,120 bytes

    if(ws_size < REQ){
        fallback_k<<<(out_size+255)/256, 256, 0, stream>>>(outp, out_size, (float)((double)ws_size*1e-6));
        return;
    }

    float* Wf   = (float*)d_ws;
    float* hs   = Wf + OFF_HS;
    float* T    = Wf + OFF_T;
    float* U    = Wf + OFF_U;
    float* sqn  = Wf + OFF_SQN;
    int*   idxb = (int*)(Wf + OFF_IDX);
    // hT aliases T region (max 16x128x1024 = 8 MB <= 16 MB); hT dead before featTU writes T
    float* hT   = T;
    // post-layer aliases (all dead regions by then):
    float* pmax   = T;                                  // 16*8*1024 = 131,072 fl
    float* colsum = T + 131072;                         // 8,192 fl
    float* pooled = T + 147456;                         // 32,768 fl
    float* z0     = T + 180224;
    float* z1     = T + 188416;
    unsigned short* wbf  = (unsigned short*)(T + 200704);   // 524,288 bf16 (inside T region)
    unsigned short* hsbf = (unsigned short*)U;              // U region (dead after layer 3)

    // ---- layer 0: h=x (S=3,D=3) -> O=64 at hs ch 0
    transpose3_k<<<64,256,0,stream>>>(x, hT);
    sqnormT_k<3><<<64,256,0,stream>>>(hT, sqn);
    knn6_k<3><<<dim3(128,16),256,0,stream>>>(hT, sqn, idxb);
    featTU_k<3,64><<<dim3(1,256),256,0,stream>>>(x, 3, th[0], ph[0], T, U);
    gather2_k<64><<<BB*NN/4,256,0,stream>>>(T, U, idxb, hs + 0);

    // ---- layer 1: h=hs[:,0:64] (S=512,D=64) -> O=64 at ch 64
    transpose_k<64><<<dim3(16,1,16),256,0,stream>>>(hs + 0, hT);
    sqnormT_k<64><<<64,256,0,stream>>>(hT, sqn);
    knn6_k<64><<<dim3(128,16),256,0,stream>>>(hT, sqn, idxb);
    featTU_k<64,64><<<dim3(1,256),256,0,stream>>>(hs + 0, 512, th[1], ph[1], T, U);
    gather2_k<64><<<BB*NN/4,256,0,stream>>>(T, U, idxb, hs + 64);

    // ---- layer 2: h=hs[:,64:128] (D=64) -> O=128 at ch 128
    transpose_k<64><<<dim3(16,1,16),256,0,stream>>>(hs + 64, hT);
    sqnormT_k<64><<<64,256,0,stream>>>(hT, sqn);
    knn6_k<64><<<dim3(128,16),256,0,stream>>>(hT, sqn, idxb);
    featTU_k<64,128><<<dim3(2,256),256,0,stream>>>(hs + 64, 512, th[2], ph[2], T, U);
    gather2_k<128><<<BB*NN/2,256,0,stream>>>(T, U, idxb, hs + 128);

    // ---- layer 3: h=hs[:,128:256] (D=128) -> O=256 at ch 256
    transpose_k<128><<<dim3(16,2,16),256,0,stream>>>(hs + 128, hT);
    sqnormT_k<128><<<64,256,0,stream>>>(hT, sqn);
    knn6_k<128><<<dim3(128,16),256,0,stream>>>(hT, sqn, idxb);
    featTU_k<128,256><<<dim3(4,256),256,0,stream>>>(hs + 128, 512, th[3], ph[3], T, U);
    gather2_k<256><<<BB*NN,256,0,stream>>>(T, U, idxb, hs + 256);

    // ---- casts (U dead now; wbf corner of T untouched by pmax/colsum/pooled/z0/z1)
    cast_hs_k<<<4096,256,0,stream>>>(hs, hsbf);
    cast_w_k<<<256,256,0,stream>>>(proj_w, wbf);

    // ---- projection + pooling (max via bf16 MFMA GEMM; mean via fp32 colsum @ w)
    proj3_k<<<1024,256,0,stream>>>(hsbf, wbf, pmax);
    colsum_k<<<32,256,0,stream>>>(hs, colsum);
    pool_final2_k<<<64,256,0,stream>>>(pmax, colsum, proj_w, proj_b, pooled);

    // ---- head
    head_bn_k<2048><<<512,256,0,stream>>>(pooled, emb0_w, emb0_b, bn0_g, bn0_b, z0, 512);
    head_bn_k<512><<<256,256,0,stream>>>(z0, emb1_w, emb1_b, bn1_g, bn1_b, z1, 256);
    head_out_k<<<40,256,0,stream>>>(z1, out_w, out_b, outp);
}